// Round 12
// baseline (795.883 us; speedup 1.0000x reference)
//
#include <hip/hip_runtime.h>
#include <math.h>

#define NROWS 8192
#define DIM   64
#define KSEL  32
#define NQ    (NROWS - KSEL)   /* 8160 query rows */
#define P1LEN 512              /* pass-1 exact prefix */
#define CAP   1024             /* per-query candidate list capacity */
#define FILT_CB 256            /* candidates per filter block */

typedef __attribute__((ext_vector_type(8))) short bf16x8;
typedef __attribute__((ext_vector_type(4))) float f32x4;

// ---------------------------------------------------------------------------
// Kernel A: row norms replicating XLA:CPU (LLVM-vectorized fused reduce):
//   VF=8 lanes, init 0, per-lane FMA chain, horizontal shuffle-tree
//   ((r0+r4)+(r2+r6)) + ((r1+r5)+(r3+r7)).   [validated bit-exact R8-R13]
// ---------------------------------------------------------------------------
__global__ void norms_kernel(const float* __restrict__ x, float* __restrict__ sq) {
    int j = blockIdx.x * blockDim.x + threadIdx.x;
    if (j >= NROWS) return;
    const float* xr = x + (size_t)j * DIM;
    float r[8];
#pragma unroll
    for (int u = 0; u < 8; ++u) r[u] = 0.0f;
#pragma unroll
    for (int i = 0; i < DIM; i += 8) {
#pragma unroll
        for (int u = 0; u < 8; ++u)
            r[u] = __fmaf_rn(xr[i + u], xr[i + u], r[u]);
    }
    const float s04 = __fadd_rn(r[0], r[4]);
    const float s26 = __fadd_rn(r[2], r[6]);
    const float s15 = __fadd_rn(r[1], r[5]);
    const float s37 = __fadd_rn(r[3], r[7]);
    sq[j] = __fadd_rn(__fadd_rn(s04, s26), __fadd_rn(s15, s37));
}

// ---------------------------------------------------------------------------
// Transpose x [8192][64] -> xT [64][8192] via LDS tile (64x64, +1 pad).
// Enables COALESCED candidate loads in pass1.
// ---------------------------------------------------------------------------
__global__ __launch_bounds__(256)
void transpose_kernel(const float* __restrict__ x, float* __restrict__ xT) {
    __shared__ float tile[64][65];
    const int jb  = blockIdx.x * 64;
    const int t   = threadIdx.x;
    const int row = t >> 2;                 // 0..63
    const int cb  = (t & 3) * 16;           // 0,16,32,48
    const float4* src = reinterpret_cast<const float4*>(
        x + (size_t)(jb + row) * DIM + cb);
#pragma unroll
    for (int i = 0; i < 4; ++i) {
        const float4 v = src[i];
        tile[row][cb + 4 * i + 0] = v.x; tile[row][cb + 4 * i + 1] = v.y;
        tile[row][cb + 4 * i + 2] = v.z; tile[row][cb + 4 * i + 3] = v.w;
    }
    __syncthreads();
    const int k = row;                      // dim index this thread writes
#pragma unroll
    for (int i = 0; i < 4; ++i) {
        float4 w;
        w.x = tile[cb + 4 * i + 0][k]; w.y = tile[cb + 4 * i + 1][k];
        w.z = tile[cb + 4 * i + 2][k]; w.w = tile[cb + 4 * i + 3][k];
        *reinterpret_cast<float4*>(xT + (size_t)k * NROWS + jb + cb + 4 * i) = w;
    }
}

// ---------------------------------------------------------------------------
// Convert x -> bf16 (RNE), 4 elems/thread.
// bf16 RNE rel-err <= 2^-8 per element -> rigorous filter margin (below).
// ---------------------------------------------------------------------------
__global__ __launch_bounds__(256)
void convert_kernel(const float* __restrict__ x, unsigned short* __restrict__ xb) {
    const int i = (blockIdx.x * blockDim.x + threadIdx.x) * 4;
    if (i >= NROWS * DIM) return;
    const float4 v = *reinterpret_cast<const float4*>(x + i);
    const float vv[4] = {v.x, v.y, v.z, v.w};
    unsigned short o[4];
#pragma unroll
    for (int u = 0; u < 4; ++u) {
        const unsigned b = __float_as_uint(vv[u]);
        o[u] = (unsigned short)((b + 0x7FFFu + ((b >> 16) & 1u)) >> 16);
    }
    *reinterpret_cast<ushort4*>(xb + i) = make_ushort4(o[0], o[1], o[2], o[3]);
}

// ---------------------------------------------------------------------------
// Pass 1 (v2, R11-validated: dropped out of top-5): exact top-32 over
// prefix [0, min(512, r)).  Coalesced xT candidate loads, 4 queries/block
// (one per wave).  Bit-exact chain preserved (multiply commutation is
// rounding-neutral).  Selection: 8 keys/lane, 32 shuffle extract-min.
// ---------------------------------------------------------------------------
__global__ __launch_bounds__(256)
void pass1_kernel(const float* __restrict__ x, const float* __restrict__ xT,
                  const float* __restrict__ sq,
                  unsigned long long* __restrict__ tau0,
                  unsigned int* __restrict__ cnt,
                  unsigned long long* __restrict__ lists) {
    const int wave = threadIdx.x >> 6;  // 0..3: independent query per wave
    const int lane = threadIdx.x & 63;
    const int qi   = blockIdx.x * 4 + wave;   // 0..8159
    const int r    = qi + KSEL;               // query row (wave-uniform)
    const int P    = min(r, P1LEN);

    const float* qp  = x + (size_t)r * DIM;   // uniform -> scalar loads
    const float  sqr = sq[r];

    float acc[8];
#pragma unroll
    for (int u = 0; u < 8; ++u) acc[u] = 0.0f;
    const float4* xT4 = reinterpret_cast<const float4*>(xT);
#pragma unroll 4
    for (int k = 0; k < DIM; ++k) {
        const float  qk = qp[k];
        const float4 c0 = xT4[(size_t)k * (NROWS / 4) + lane];       // j=4l..+3
        const float4 c1 = xT4[(size_t)k * (NROWS / 4) + 64 + lane];  // j=256+4l..+3
        acc[0] = __fmaf_rn(qk, c0.x, acc[0]);
        acc[1] = __fmaf_rn(qk, c0.y, acc[1]);
        acc[2] = __fmaf_rn(qk, c0.z, acc[2]);
        acc[3] = __fmaf_rn(qk, c0.w, acc[3]);
        acc[4] = __fmaf_rn(qk, c1.x, acc[4]);
        acc[5] = __fmaf_rn(qk, c1.y, acc[5]);
        acc[6] = __fmaf_rn(qk, c1.z, acc[6]);
        acc[7] = __fmaf_rn(qk, c1.w, acc[7]);
    }

    unsigned long long key[8];
    {
        const float4 sq0 = *reinterpret_cast<const float4*>(sq + 4 * lane);
        const float4 sq1 = *reinterpret_cast<const float4*>(sq + 256 + 4 * lane);
        const float sqc[8] = {sq0.x, sq0.y, sq0.z, sq0.w,
                              sq1.x, sq1.y, sq1.z, sq1.w};
#pragma unroll
        for (int u = 0; u < 8; ++u) {
            const int j = (u < 4) ? (4 * lane + u) : (256 + 4 * lane + (u - 4));
            const float dd = fmaxf(
                __fsub_rn(__fadd_rn(sqr, sqc[u]), __fmul_rn(2.0f, acc[u])), 0.0f);
            key[u] = (j < P)
                ? (((unsigned long long)__float_as_uint(dd) << 32) | (unsigned)j)
                : ~0ull;
        }
    }

    unsigned long long pmin = ~0ull;
#pragma unroll
    for (int s = 0; s < 8; ++s) pmin = key[s] < pmin ? key[s] : pmin;

    unsigned long long g = ~0ull;
    for (int it = 0; it < KSEL; ++it) {
        unsigned long long v = pmin;
#pragma unroll
        for (int off = 32; off > 0; off >>= 1) {
            const unsigned long long o = __shfl_down(v, off, 64);
            v = o < v ? o : v;
        }
        g = __shfl(v, 0, 64);
        if (lane == 0) lists[(size_t)qi * CAP + it] = g;
        if (pmin == g) {            // unique winner (keys embed unique j)
#pragma unroll
            for (int s = 0; s < 8; ++s) if (key[s] == g) key[s] = ~0ull;
            pmin = ~0ull;
#pragma unroll
            for (int s = 0; s < 8; ++s) pmin = key[s] < pmin ? key[s] : pmin;
        }
    }
    if (lane == 0) { tau0[qi] = g; cnt[qi] = KSEL; }
}

// ---------------------------------------------------------------------------
// Filter (v9): FUSED bf16-MFMA screen + exact fp32 refine over [512, r).
// R11 POST-MORTEM: separate refine (97us) was a latency-bound gather (each
// lane chasing a 256-B row, Occ 30%, VALU 4.8%); filter's 45MB WRITE_SIZE
// was scattered approx-entry appends thrashing L2 write-allocate.  v9:
//   * screen unchanged (R9-validated fragments); margin tightened to the
//     still-rigorous 1.5*2^-7*S  (2*|dot err| <= 2^-6*||q||||c|| <= 2^-7*S;
//     1.5x slack covers bf16-product + fp32-accum rounding).
//   * accepting lanes IMMEDIATELY run the exact VALIDATED fp32 chain
//     (k=0..63 ascending, float4 x/y/z/w -- refine's exact code): q row is
//     L1-hot (64 rows/block, 30x reuse), c row L2-hot (x = 2MB).  SIMT
//     predication runs all accepting lanes' chains in parallel.
//   * ONLY exact survivors (bits <= th) are appended -> write-once lists,
//     no refine pass, no CAP-overflow risk (max ~480 < 1024).
// Accepted set provably identical to screen+refine.  No separate refine.
// ---------------------------------------------------------------------------
__global__ __launch_bounds__(256)
void filter_kernel(const float* __restrict__ x,
                   const unsigned short* __restrict__ xb,
                   const float* __restrict__ sq,
                   const unsigned long long* __restrict__ tau0,
                   unsigned int* __restrict__ cnt,
                   unsigned long long* __restrict__ lists) {
    const int qb   = blockIdx.x;                        // 64-query tile
    const int jb   = P1LEN + blockIdx.y * FILT_CB;      // candidate tile base
    const int r_hi = min(KSEL + (qb + 1) * 64, NROWS);  // exclusive query cap
    if (jb >= r_hi) return;                             // uniform exit

    const int wave = threadIdx.x >> 6;                  // 0..3
    const int lane = threadIdx.x & 63;
    const int rb   = KSEL + qb * 64 + wave * 16;        // wave's first q row
    const int col  = lane & 15;
    const int kg   = lane >> 4;                         // k-group 0..3

    // A fragments (row rb+col, k = kg*8 + {0..7} and +32): contiguous 16B
    const int arow = min(rb + col, NROWS - 1);
    const bf16x8 a0 = *reinterpret_cast<const bf16x8*>(xb + (size_t)arow * DIM + kg * 8);
    const bf16x8 a1 = *reinterpret_cast<const bf16x8*>(xb + (size_t)arow * DIM + 32 + kg * 8);

    // Epilogue per-lane row data: D rows rb + kg*4 + i
    float sqr[4], thm[4]; int rr[4]; unsigned thb[4];
#pragma unroll
    for (int i = 0; i < 4; ++i) {
        const int r = rb + kg * 4 + i;
        rr[i]  = r;
        const int rc = min(r, NROWS - 1);
        sqr[i] = sq[rc];
        thb[i] = (r < NROWS) ? (unsigned)(tau0[r - KSEL] >> 32) : 0u;
        thm[i] = (r < NROWS) ? __uint_as_float(thb[i]) : -1.0f;  // reject all
    }

    for (int sub = 0; sub < FILT_CB / 16; ++sub) {
        const int j0 = jb + sub * 16;
        if (j0 >= r_hi) break;                          // wave-uniform
        const int j  = j0 + col;
        const int jc = min(j, NROWS - 1);
        const bf16x8 b0 = *reinterpret_cast<const bf16x8*>(xb + (size_t)jc * DIM + kg * 8);
        const bf16x8 b1 = *reinterpret_cast<const bf16x8*>(xb + (size_t)jc * DIM + 32 + kg * 8);
        f32x4 acc = {0.f, 0.f, 0.f, 0.f};
        acc = __builtin_amdgcn_mfma_f32_16x16x32_bf16(a0, b0, acc, 0, 0, 0);
        acc = __builtin_amdgcn_mfma_f32_16x16x32_bf16(a1, b1, acc, 0, 0, 0);
        const float sqc = sq[jc];
#pragma unroll
        for (int i = 0; i < 4; ++i) {
            const float s = __fadd_rn(sqr[i], sqc);
            const float d = __fmaf_rn(-2.0f, acc[i], s);
            const bool cand = (j < rr[i]) && (rr[i] < NROWS) &&
                              (d <= __fmaf_rn(0.01171875f, s, thm[i]));
            // ---- fused exact refine for screening survivors (predicated)
            bool keep = false; unsigned ebits = 0u;
            if (cand) {
                const float* qp = x + (size_t)rr[i] * DIM;   // L1-hot
                const float* cp = x + (size_t)j * DIM;       // L2-hot
                float acx = 0.0f;
#pragma unroll
                for (int k = 0; k < DIM; k += 4) {
                    const float4 qv = *reinterpret_cast<const float4*>(qp + k);
                    const float4 cv = *reinterpret_cast<const float4*>(cp + k);
                    acx = __fmaf_rn(qv.x, cv.x, acx);
                    acx = __fmaf_rn(qv.y, cv.y, acx);
                    acx = __fmaf_rn(qv.z, cv.z, acx);
                    acx = __fmaf_rn(qv.w, cv.w, acx);
                }
                const float dd = fmaxf(
                    __fsub_rn(__fadd_rn(sqr[i], sqc), __fmul_rn(2.0f, acx)), 0.0f);
                ebits = __float_as_uint(dd);
                keep  = (ebits <= thb[i]);
            }
            const unsigned long long mask = __ballot(keep);
            const unsigned slice = (unsigned)((mask >> (kg * 16)) & 0xFFFFull);
            if (slice) {
                const int qi = rr[i] - KSEL;            // valid: slice!=0 => keeps
                const int leader = kg * 16 + (int)__builtin_ctz(slice);
                unsigned base = 0;
                if (lane == leader)
                    base = atomicAdd(&cnt[qi], (unsigned)__popc(slice));
                base = __shfl(base, leader, 64);
                if (keep) {
                    const unsigned slot =
                        base + (unsigned)__popc(slice & ((1u << col) - 1u));
                    if (slot < CAP)
                        lists[(size_t)qi * CAP + slot] =
                            ((unsigned long long)ebits << 32) | (unsigned)j;
                }
            }
        }
    }
}

// ---------------------------------------------------------------------------
// Merge: ONE WAVE per query.  16 keys/lane in registers, 32 shuffle-only
// extract-min iterations.  u64-min = ascending (dist, index), low-index
// ties (validated top_k semantics).  List is a superset of the true top-32;
// all entries carry EXACT validated distance bits.
// ---------------------------------------------------------------------------
__global__ __launch_bounds__(64)
void merge_kernel(const unsigned long long* __restrict__ lists,
                  const unsigned int* __restrict__ cnt,
                  float* __restrict__ out_d, float* __restrict__ out_i) {
    const int qi   = blockIdx.x;     // 0..8159
    const int lane = threadIdx.x;
    const int ne   = min((int)cnt[qi], CAP);
    const unsigned long long* src = lists + (size_t)qi * CAP;

    unsigned long long k[16];
#pragma unroll
    for (int s = 0; s < 16; ++s) {
        const int idx = lane + (s << 6);
        k[s] = (idx < ne) ? src[idx] : ~0ull;
    }
    unsigned long long pmin = ~0ull;
#pragma unroll
    for (int s = 0; s < 16; ++s) pmin = k[s] < pmin ? k[s] : pmin;

    for (int it = 0; it < KSEL; ++it) {
        unsigned long long v = pmin;
#pragma unroll
        for (int off = 32; off > 0; off >>= 1) {
            const unsigned long long o = __shfl_down(v, off, 64);
            v = o < v ? o : v;
        }
        const unsigned long long g = __shfl(v, 0, 64);
        if (lane == 0) {
            out_d[(size_t)qi * KSEL + it] = __uint_as_float((unsigned)(g >> 32));
            out_i[(size_t)qi * KSEL + it] = (float)(unsigned)(g & 0xFFFFFFFFu);
        }
        if (pmin == g) {            // unique winner rescans its registers
#pragma unroll
            for (int s = 0; s < 16; ++s) if (k[s] == g) k[s] = ~0ull;
            pmin = ~0ull;
#pragma unroll
            for (int s = 0; s < 16; ++s) pmin = k[s] < pmin ? k[s] : pmin;
        }
    }
}

extern "C" void kernel_launch(void* const* d_in, const int* in_sizes, int n_in,
                              void* d_out, int out_size, void* d_ws, size_t ws_size,
                              hipStream_t stream) {
    const float* x = (const float*)d_in[0];    // anchor_x [8192, 64] fp32
    float* sq = (float*)d_ws;                                        // 32 KB
    unsigned long long* tau0 =
        (unsigned long long*)((char*)d_ws + 32768);                  // 64 KB
    unsigned int* cnt = (unsigned int*)((char*)d_ws + 98304);        // 32 KB
    unsigned long long* lists =
        (unsigned long long*)((char*)d_ws + 131072);                 // 66.8 MB
    unsigned short* xb =
        (unsigned short*)((char*)d_ws + 66977792);                   // 1 MB bf16
    float* xT = (float*)((char*)d_ws + 68026368);                    // 2 MB fp32
    float* out_d = (float*)d_out;              // [8160, 32] distances
    float* out_i = out_d + (size_t)NQ * KSEL;  // [8160, 32] indices (as fp32)

    norms_kernel<<<NROWS / 256, 256, 0, stream>>>(x, sq);
    transpose_kernel<<<NROWS / 64, 256, 0, stream>>>(x, xT);
    convert_kernel<<<NROWS * DIM / 1024, 256, 0, stream>>>(x, xb);
    pass1_kernel<<<NQ / 4, 256, 0, stream>>>(x, xT, sq, tau0, cnt, lists);
    dim3 gf(128, (NROWS - P1LEN) / FILT_CB);   // (query tile, candidate tile)
    filter_kernel<<<gf, 256, 0, stream>>>(x, xb, sq, tau0, cnt, lists);
    merge_kernel<<<NQ, 64, 0, stream>>>(lists, cnt, out_d, out_i);
}

// Round 13
// 378.328 us; speedup vs baseline: 2.1037x; 2.1037x over previous
//
#include <hip/hip_runtime.h>
#include <math.h>

#define NROWS 8192
#define DIM   64
#define KSEL  32
#define NQ    (NROWS - KSEL)   /* 8160 query rows */
#define P1LEN 512              /* pass-1 exact prefix */
#define CAP   1024             /* per-query candidate list capacity */
#define FILT_CB 256            /* candidates per filter block */

typedef __attribute__((ext_vector_type(8))) short bf16x8;
typedef __attribute__((ext_vector_type(4))) float f32x4;

// ---------------------------------------------------------------------------
// Kernel A: row norms replicating XLA:CPU (LLVM-vectorized fused reduce):
//   VF=8 lanes, init 0, per-lane FMA chain, horizontal shuffle-tree
//   ((r0+r4)+(r2+r6)) + ((r1+r5)+(r3+r7)).   [validated bit-exact R8-R13]
// ---------------------------------------------------------------------------
__global__ void norms_kernel(const float* __restrict__ x, float* __restrict__ sq) {
    int j = blockIdx.x * blockDim.x + threadIdx.x;
    if (j >= NROWS) return;
    const float* xr = x + (size_t)j * DIM;
    float r[8];
#pragma unroll
    for (int u = 0; u < 8; ++u) r[u] = 0.0f;
#pragma unroll
    for (int i = 0; i < DIM; i += 8) {
#pragma unroll
        for (int u = 0; u < 8; ++u)
            r[u] = __fmaf_rn(xr[i + u], xr[i + u], r[u]);
    }
    const float s04 = __fadd_rn(r[0], r[4]);
    const float s26 = __fadd_rn(r[2], r[6]);
    const float s15 = __fadd_rn(r[1], r[5]);
    const float s37 = __fadd_rn(r[3], r[7]);
    sq[j] = __fadd_rn(__fadd_rn(s04, s26), __fadd_rn(s15, s37));
}

// ---------------------------------------------------------------------------
// Transpose x [8192][64] -> xT [64][8192] via LDS tile (64x64, +1 pad).
// Enables COALESCED candidate loads in pass1.
// ---------------------------------------------------------------------------
__global__ __launch_bounds__(256)
void transpose_kernel(const float* __restrict__ x, float* __restrict__ xT) {
    __shared__ float tile[64][65];
    const int jb  = blockIdx.x * 64;
    const int t   = threadIdx.x;
    const int row = t >> 2;                 // 0..63
    const int cb  = (t & 3) * 16;           // 0,16,32,48
    const float4* src = reinterpret_cast<const float4*>(
        x + (size_t)(jb + row) * DIM + cb);
#pragma unroll
    for (int i = 0; i < 4; ++i) {
        const float4 v = src[i];
        tile[row][cb + 4 * i + 0] = v.x; tile[row][cb + 4 * i + 1] = v.y;
        tile[row][cb + 4 * i + 2] = v.z; tile[row][cb + 4 * i + 3] = v.w;
    }
    __syncthreads();
    const int k = row;                      // dim index this thread writes
#pragma unroll
    for (int i = 0; i < 4; ++i) {
        float4 w;
        w.x = tile[cb + 4 * i + 0][k]; w.y = tile[cb + 4 * i + 1][k];
        w.z = tile[cb + 4 * i + 2][k]; w.w = tile[cb + 4 * i + 3][k];
        *reinterpret_cast<float4*>(xT + (size_t)k * NROWS + jb + cb + 4 * i) = w;
    }
}

// ---------------------------------------------------------------------------
// Convert x -> bf16 (RNE), 4 elems/thread.
// bf16 RNE rel-err <= 2^-8 per element -> rigorous filter margin (below).
// ---------------------------------------------------------------------------
__global__ __launch_bounds__(256)
void convert_kernel(const float* __restrict__ x, unsigned short* __restrict__ xb) {
    const int i = (blockIdx.x * blockDim.x + threadIdx.x) * 4;
    if (i >= NROWS * DIM) return;
    const float4 v = *reinterpret_cast<const float4*>(x + i);
    const float vv[4] = {v.x, v.y, v.z, v.w};
    unsigned short o[4];
#pragma unroll
    for (int u = 0; u < 4; ++u) {
        const unsigned b = __float_as_uint(vv[u]);
        o[u] = (unsigned short)((b + 0x7FFFu + ((b >> 16) & 1u)) >> 16);
    }
    *reinterpret_cast<ushort4*>(xb + i) = make_ushort4(o[0], o[1], o[2], o[3]);
}

// ---------------------------------------------------------------------------
// Pass 1 (v2, R11-validated: dropped out of top-5): exact top-32 over
// prefix [0, min(512, r)).  Coalesced xT candidate loads, 4 queries/block
// (one per wave).  Bit-exact chain preserved (multiply commutation is
// rounding-neutral).  Selection: 8 keys/lane, 32 shuffle extract-min.
// ---------------------------------------------------------------------------
__global__ __launch_bounds__(256)
void pass1_kernel(const float* __restrict__ x, const float* __restrict__ xT,
                  const float* __restrict__ sq,
                  unsigned long long* __restrict__ tau0,
                  unsigned int* __restrict__ cnt,
                  unsigned long long* __restrict__ lists) {
    const int wave = threadIdx.x >> 6;  // 0..3: independent query per wave
    const int lane = threadIdx.x & 63;
    const int qi   = blockIdx.x * 4 + wave;   // 0..8159
    const int r    = qi + KSEL;               // query row (wave-uniform)
    const int P    = min(r, P1LEN);

    const float* qp  = x + (size_t)r * DIM;   // uniform -> scalar loads
    const float  sqr = sq[r];

    float acc[8];
#pragma unroll
    for (int u = 0; u < 8; ++u) acc[u] = 0.0f;
    const float4* xT4 = reinterpret_cast<const float4*>(xT);
#pragma unroll 4
    for (int k = 0; k < DIM; ++k) {
        const float  qk = qp[k];
        const float4 c0 = xT4[(size_t)k * (NROWS / 4) + lane];       // j=4l..+3
        const float4 c1 = xT4[(size_t)k * (NROWS / 4) + 64 + lane];  // j=256+4l..+3
        acc[0] = __fmaf_rn(qk, c0.x, acc[0]);
        acc[1] = __fmaf_rn(qk, c0.y, acc[1]);
        acc[2] = __fmaf_rn(qk, c0.z, acc[2]);
        acc[3] = __fmaf_rn(qk, c0.w, acc[3]);
        acc[4] = __fmaf_rn(qk, c1.x, acc[4]);
        acc[5] = __fmaf_rn(qk, c1.y, acc[5]);
        acc[6] = __fmaf_rn(qk, c1.z, acc[6]);
        acc[7] = __fmaf_rn(qk, c1.w, acc[7]);
    }

    unsigned long long key[8];
    {
        const float4 sq0 = *reinterpret_cast<const float4*>(sq + 4 * lane);
        const float4 sq1 = *reinterpret_cast<const float4*>(sq + 256 + 4 * lane);
        const float sqc[8] = {sq0.x, sq0.y, sq0.z, sq0.w,
                              sq1.x, sq1.y, sq1.z, sq1.w};
#pragma unroll
        for (int u = 0; u < 8; ++u) {
            const int j = (u < 4) ? (4 * lane + u) : (256 + 4 * lane + (u - 4));
            const float dd = fmaxf(
                __fsub_rn(__fadd_rn(sqr, sqc[u]), __fmul_rn(2.0f, acc[u])), 0.0f);
            key[u] = (j < P)
                ? (((unsigned long long)__float_as_uint(dd) << 32) | (unsigned)j)
                : ~0ull;
        }
    }

    unsigned long long pmin = ~0ull;
#pragma unroll
    for (int s = 0; s < 8; ++s) pmin = key[s] < pmin ? key[s] : pmin;

    unsigned long long g = ~0ull;
    for (int it = 0; it < KSEL; ++it) {
        unsigned long long v = pmin;
#pragma unroll
        for (int off = 32; off > 0; off >>= 1) {
            const unsigned long long o = __shfl_down(v, off, 64);
            v = o < v ? o : v;
        }
        g = __shfl(v, 0, 64);
        if (lane == 0) lists[(size_t)qi * CAP + it] = g;
        if (pmin == g) {            // unique winner (keys embed unique j)
#pragma unroll
            for (int s = 0; s < 8; ++s) if (key[s] == g) key[s] = ~0ull;
            pmin = ~0ull;
#pragma unroll
            for (int s = 0; s < 8; ++s) pmin = key[s] < pmin ? key[s] : pmin;
        }
    }
    if (lane == 0) { tau0[qi] = g; cnt[qi] = KSEL; }
}

// ---------------------------------------------------------------------------
// Filter (v10 = R11's screen-only v8, R12-validated tighter margin):
// bf16 MFMA screen over [512, r).  R12 POST-MORTEM: fusing the exact chain
// in here ran a serial 64-FMA gather-fed chain whenever ANY of a 16-slice's
// lanes was a candidate (~34% of slices) -> 630us.  Screen-only + separate
// MLP-refine is the right split.  Margin 1.5*2^-7*S is rigorous:
// 2*|dot err| <= 2^-6*||q||||c|| <= 2^-7*S, 1.5x slack for bf16-product +
// fp32-accum rounding.  Appends approx entries to lists via one atomic per
// 16-lane slice (8160 spread addresses -- R9-proven cheap).
// ---------------------------------------------------------------------------
__global__ __launch_bounds__(256)
void filter_kernel(const unsigned short* __restrict__ xb,
                   const float* __restrict__ sq,
                   const unsigned long long* __restrict__ tau0,
                   unsigned int* __restrict__ cnt,
                   unsigned long long* __restrict__ lists) {
    const int qb   = blockIdx.x;                        // 64-query tile
    const int jb   = P1LEN + blockIdx.y * FILT_CB;      // candidate tile base
    const int r_hi = min(KSEL + (qb + 1) * 64, NROWS);  // exclusive query cap
    if (jb >= r_hi) return;                             // uniform exit

    const int wave = threadIdx.x >> 6;                  // 0..3
    const int lane = threadIdx.x & 63;
    const int rb   = KSEL + qb * 64 + wave * 16;        // wave's first q row
    const int col  = lane & 15;
    const int kg   = lane >> 4;                         // k-group 0..3

    // A fragments (row rb+col, k = kg*8 + {0..7} and +32): contiguous 16B
    const int arow = min(rb + col, NROWS - 1);
    const bf16x8 a0 = *reinterpret_cast<const bf16x8*>(xb + (size_t)arow * DIM + kg * 8);
    const bf16x8 a1 = *reinterpret_cast<const bf16x8*>(xb + (size_t)arow * DIM + 32 + kg * 8);

    // Epilogue per-lane row data: D rows rb + kg*4 + i
    float sqr[4], thm[4]; int rr[4];
#pragma unroll
    for (int i = 0; i < 4; ++i) {
        const int r = rb + kg * 4 + i;
        rr[i]  = r;
        const int rc = min(r, NROWS - 1);
        sqr[i] = sq[rc];
        thm[i] = (r < NROWS) ? __uint_as_float((unsigned)(tau0[r - KSEL] >> 32))
                             : -1.0f;                   // reject all
    }

    for (int sub = 0; sub < FILT_CB / 16; ++sub) {
        const int j0 = jb + sub * 16;
        if (j0 >= r_hi) break;                          // wave-uniform
        const int j  = j0 + col;
        const int jc = min(j, NROWS - 1);
        const bf16x8 b0 = *reinterpret_cast<const bf16x8*>(xb + (size_t)jc * DIM + kg * 8);
        const bf16x8 b1 = *reinterpret_cast<const bf16x8*>(xb + (size_t)jc * DIM + 32 + kg * 8);
        f32x4 acc = {0.f, 0.f, 0.f, 0.f};
        acc = __builtin_amdgcn_mfma_f32_16x16x32_bf16(a0, b0, acc, 0, 0, 0);
        acc = __builtin_amdgcn_mfma_f32_16x16x32_bf16(a1, b1, acc, 0, 0, 0);
        const float sqc = sq[jc];
#pragma unroll
        for (int i = 0; i < 4; ++i) {
            const float s = __fadd_rn(sqr[i], sqc);
            const float d = __fmaf_rn(-2.0f, acc[i], s);
            const bool accept = (j < rr[i]) && (rr[i] < NROWS) &&
                                (d <= __fmaf_rn(0.01171875f, s, thm[i]));
            const unsigned long long mask = __ballot(accept);
            const unsigned slice = (unsigned)((mask >> (kg * 16)) & 0xFFFFull);
            if (slice) {
                const int qi = rr[i] - KSEL;            // valid: slice!=0 => accepts
                const int leader = kg * 16 + (int)__builtin_ctz(slice);
                unsigned base = 0;
                if (lane == leader)
                    base = atomicAdd(&cnt[qi], (unsigned)__popc(slice));
                base = __shfl(base, leader, 64);
                if (accept) {
                    const unsigned slot =
                        base + (unsigned)__popc(slice & ((1u << col) - 1u));
                    if (slot < CAP)
                        lists[(size_t)qi * CAP + slot] =
                            ((unsigned long long)__float_as_uint(fmaxf(d, 0.0f)) << 32)
                            | (unsigned)j;
                }
            }
        }
    }
}

// ---------------------------------------------------------------------------
// Refine (v2): 4 queries/block (one wave each).  R11 POST-MORTEM: v1
// (64-thr blocks, dependent load->FMA pairs) was latency-bound (VALU 4.8%,
// Occ 30%, 97us).  v2 adds MLP: the candidate row is PREFETCHED into 16
// float4 regs (16 independent loads in flight) BEFORE the chain; 256-thr
// blocks lift residency; launch_bounds(256,3) caps VGPR at 170 >> ~95 live
// (avoids the R3/R4 allocator-starvation spill).  Chain unchanged: exact
// VALIDATED fp32 k=0..63 ascending, float4 x/y/z/w.  Entries >= 32 are
// rewritten in place: keep iff bits <= tau_hi else ~0ull (inert in merge).
// ---------------------------------------------------------------------------
__global__ __launch_bounds__(256, 3)
void refine_kernel(const float* __restrict__ x, const float* __restrict__ sq,
                   const unsigned long long* __restrict__ tau0,
                   const unsigned int* __restrict__ cnt,
                   unsigned long long* __restrict__ lists) {
    const int wave = threadIdx.x >> 6;
    const int lane = threadIdx.x & 63;
    const int qi   = blockIdx.x * 4 + wave;   // 0..8159
    const int r    = qi + KSEL;
    const int ne   = min((int)cnt[qi], CAP);
    const unsigned th = (unsigned)(tau0[qi] >> 32);
    const float* qp = x + (size_t)r * DIM;    // wave-uniform -> scalar loads
    const float  sqr = sq[r];
    unsigned long long* dst = lists + (size_t)qi * CAP;

    for (int s = KSEL + lane; s < ne; s += 64) {
        const int j = (int)(unsigned)(dst[s] & 0xFFFFFFFFu);
        const float4* cp4 = reinterpret_cast<const float4*>(x + (size_t)j * DIM);
        float4 c[16];
#pragma unroll
        for (int k = 0; k < 16; ++k) c[k] = cp4[k];   // 16 loads in flight (MLP)
        float acc = 0.0f;
#pragma unroll
        for (int k = 0; k < 16; ++k) {
            acc = __fmaf_rn(qp[4 * k + 0], c[k].x, acc);
            acc = __fmaf_rn(qp[4 * k + 1], c[k].y, acc);
            acc = __fmaf_rn(qp[4 * k + 2], c[k].z, acc);
            acc = __fmaf_rn(qp[4 * k + 3], c[k].w, acc);
        }
        const float dd = fmaxf(
            __fsub_rn(__fadd_rn(sqr, sq[j]), __fmul_rn(2.0f, acc)), 0.0f);
        const unsigned bits = __float_as_uint(dd);
        dst[s] = (bits <= th)
                   ? (((unsigned long long)bits << 32) | (unsigned)j)
                   : ~0ull;
    }
}

// ---------------------------------------------------------------------------
// Merge: ONE WAVE per query.  16 keys/lane in registers, 32 shuffle-only
// extract-min iterations.  u64-min = ascending (dist, index), low-index
// ties (validated top_k semantics).  List is a superset of the true top-32.
// ---------------------------------------------------------------------------
__global__ __launch_bounds__(64)
void merge_kernel(const unsigned long long* __restrict__ lists,
                  const unsigned int* __restrict__ cnt,
                  float* __restrict__ out_d, float* __restrict__ out_i) {
    const int qi   = blockIdx.x;     // 0..8159
    const int lane = threadIdx.x;
    const int ne   = min((int)cnt[qi], CAP);
    const unsigned long long* src = lists + (size_t)qi * CAP;

    unsigned long long k[16];
#pragma unroll
    for (int s = 0; s < 16; ++s) {
        const int idx = lane + (s << 6);
        k[s] = (idx < ne) ? src[idx] : ~0ull;
    }
    unsigned long long pmin = ~0ull;
#pragma unroll
    for (int s = 0; s < 16; ++s) pmin = k[s] < pmin ? k[s] : pmin;

    for (int it = 0; it < KSEL; ++it) {
        unsigned long long v = pmin;
#pragma unroll
        for (int off = 32; off > 0; off >>= 1) {
            const unsigned long long o = __shfl_down(v, off, 64);
            v = o < v ? o : v;
        }
        const unsigned long long g = __shfl(v, 0, 64);
        if (lane == 0) {
            out_d[(size_t)qi * KSEL + it] = __uint_as_float((unsigned)(g >> 32));
            out_i[(size_t)qi * KSEL + it] = (float)(unsigned)(g & 0xFFFFFFFFu);
        }
        if (pmin == g) {            // unique winner rescans its registers
#pragma unroll
            for (int s = 0; s < 16; ++s) if (k[s] == g) k[s] = ~0ull;
            pmin = ~0ull;
#pragma unroll
            for (int s = 0; s < 16; ++s) pmin = k[s] < pmin ? k[s] : pmin;
        }
    }
}

extern "C" void kernel_launch(void* const* d_in, const int* in_sizes, int n_in,
                              void* d_out, int out_size, void* d_ws, size_t ws_size,
                              hipStream_t stream) {
    const float* x = (const float*)d_in[0];    // anchor_x [8192, 64] fp32
    float* sq = (float*)d_ws;                                        // 32 KB
    unsigned long long* tau0 =
        (unsigned long long*)((char*)d_ws + 32768);                  // 64 KB
    unsigned int* cnt = (unsigned int*)((char*)d_ws + 98304);        // 32 KB
    unsigned long long* lists =
        (unsigned long long*)((char*)d_ws + 131072);                 // 66.8 MB
    unsigned short* xb =
        (unsigned short*)((char*)d_ws + 66977792);                   // 1 MB bf16
    float* xT = (float*)((char*)d_ws + 68026368);                    // 2 MB fp32
    float* out_d = (float*)d_out;              // [8160, 32] distances
    float* out_i = out_d + (size_t)NQ * KSEL;  // [8160, 32] indices (as fp32)

    norms_kernel<<<NROWS / 256, 256, 0, stream>>>(x, sq);
    transpose_kernel<<<NROWS / 64, 256, 0, stream>>>(x, xT);
    convert_kernel<<<NROWS * DIM / 1024, 256, 0, stream>>>(x, xb);
    pass1_kernel<<<NQ / 4, 256, 0, stream>>>(x, xT, sq, tau0, cnt, lists);
    dim3 gf(128, (NROWS - P1LEN) / FILT_CB);   // (query tile, candidate tile)
    filter_kernel<<<gf, 256, 0, stream>>>(xb, sq, tau0, cnt, lists);
    refine_kernel<<<NQ / 4, 256, 0, stream>>>(x, sq, tau0, cnt, lists);
    merge_kernel<<<NQ, 64, 0, stream>>>(lists, cnt, out_d, out_i);
}

// Round 14
// 357.378 us; speedup vs baseline: 2.2270x; 1.0586x over previous
//
#include <hip/hip_runtime.h>
#include <math.h>

#define NROWS 8192
#define DIM   64
#define KSEL  32
#define NQ    (NROWS - KSEL)   /* 8160 query rows */
#define P1LEN 512              /* pass-1 exact prefix */
#define CAP   1024             /* per-query candidate list capacity */
#define FILT_CB 256            /* candidates per filter block */

typedef __attribute__((ext_vector_type(8))) short bf16x8;
typedef __attribute__((ext_vector_type(4))) float f32x4;

// ---------------------------------------------------------------------------
// Kernel A: row norms replicating XLA:CPU (LLVM-vectorized fused reduce):
//   VF=8 lanes, init 0, per-lane FMA chain, horizontal shuffle-tree
//   ((r0+r4)+(r2+r6)) + ((r1+r5)+(r3+r7)).   [validated bit-exact R8-R13]
// ---------------------------------------------------------------------------
__global__ void norms_kernel(const float* __restrict__ x, float* __restrict__ sq) {
    int j = blockIdx.x * blockDim.x + threadIdx.x;
    if (j >= NROWS) return;
    const float* xr = x + (size_t)j * DIM;
    float r[8];
#pragma unroll
    for (int u = 0; u < 8; ++u) r[u] = 0.0f;
#pragma unroll
    for (int i = 0; i < DIM; i += 8) {
#pragma unroll
        for (int u = 0; u < 8; ++u)
            r[u] = __fmaf_rn(xr[i + u], xr[i + u], r[u]);
    }
    const float s04 = __fadd_rn(r[0], r[4]);
    const float s26 = __fadd_rn(r[2], r[6]);
    const float s15 = __fadd_rn(r[1], r[5]);
    const float s37 = __fadd_rn(r[3], r[7]);
    sq[j] = __fadd_rn(__fadd_rn(s04, s26), __fadd_rn(s15, s37));
}

// ---------------------------------------------------------------------------
// Transpose x [8192][64] -> xT [64][8192] via LDS tile (64x64, +1 pad).
// Enables COALESCED candidate loads in pass1.
// ---------------------------------------------------------------------------
__global__ __launch_bounds__(256)
void transpose_kernel(const float* __restrict__ x, float* __restrict__ xT) {
    __shared__ float tile[64][65];
    const int jb  = blockIdx.x * 64;
    const int t   = threadIdx.x;
    const int row = t >> 2;                 // 0..63
    const int cb  = (t & 3) * 16;           // 0,16,32,48
    const float4* src = reinterpret_cast<const float4*>(
        x + (size_t)(jb + row) * DIM + cb);
#pragma unroll
    for (int i = 0; i < 4; ++i) {
        const float4 v = src[i];
        tile[row][cb + 4 * i + 0] = v.x; tile[row][cb + 4 * i + 1] = v.y;
        tile[row][cb + 4 * i + 2] = v.z; tile[row][cb + 4 * i + 3] = v.w;
    }
    __syncthreads();
    const int k = row;                      // dim index this thread writes
#pragma unroll
    for (int i = 0; i < 4; ++i) {
        float4 w;
        w.x = tile[cb + 4 * i + 0][k]; w.y = tile[cb + 4 * i + 1][k];
        w.z = tile[cb + 4 * i + 2][k]; w.w = tile[cb + 4 * i + 3][k];
        *reinterpret_cast<float4*>(xT + (size_t)k * NROWS + jb + cb + 4 * i) = w;
    }
}

// ---------------------------------------------------------------------------
// Convert x -> bf16 (RNE), 4 elems/thread.
// bf16 RNE rel-err <= 2^-8 per element -> rigorous filter margin (below).
// ---------------------------------------------------------------------------
__global__ __launch_bounds__(256)
void convert_kernel(const float* __restrict__ x, unsigned short* __restrict__ xb) {
    const int i = (blockIdx.x * blockDim.x + threadIdx.x) * 4;
    if (i >= NROWS * DIM) return;
    const float4 v = *reinterpret_cast<const float4*>(x + i);
    const float vv[4] = {v.x, v.y, v.z, v.w};
    unsigned short o[4];
#pragma unroll
    for (int u = 0; u < 4; ++u) {
        const unsigned b = __float_as_uint(vv[u]);
        o[u] = (unsigned short)((b + 0x7FFFu + ((b >> 16) & 1u)) >> 16);
    }
    *reinterpret_cast<ushort4*>(xb + i) = make_ushort4(o[0], o[1], o[2], o[3]);
}

// ---------------------------------------------------------------------------
// Pass 1 (v2, R11-validated: dropped out of top-5): exact top-32 over
// prefix [0, min(512, r)).  Coalesced xT candidate loads, 4 queries/block
// (one per wave).  Bit-exact chain preserved (multiply commutation is
// rounding-neutral).  Selection: 8 keys/lane, 32 shuffle extract-min.
// ---------------------------------------------------------------------------
__global__ __launch_bounds__(256)
void pass1_kernel(const float* __restrict__ x, const float* __restrict__ xT,
                  const float* __restrict__ sq,
                  unsigned long long* __restrict__ tau0,
                  unsigned int* __restrict__ cnt,
                  unsigned long long* __restrict__ lists) {
    const int wave = threadIdx.x >> 6;  // 0..3: independent query per wave
    const int lane = threadIdx.x & 63;
    const int qi   = blockIdx.x * 4 + wave;   // 0..8159
    const int r    = qi + KSEL;               // query row (wave-uniform)
    const int P    = min(r, P1LEN);

    const float* qp  = x + (size_t)r * DIM;   // uniform -> scalar loads
    const float  sqr = sq[r];

    float acc[8];
#pragma unroll
    for (int u = 0; u < 8; ++u) acc[u] = 0.0f;
    const float4* xT4 = reinterpret_cast<const float4*>(xT);
#pragma unroll 4
    for (int k = 0; k < DIM; ++k) {
        const float  qk = qp[k];
        const float4 c0 = xT4[(size_t)k * (NROWS / 4) + lane];       // j=4l..+3
        const float4 c1 = xT4[(size_t)k * (NROWS / 4) + 64 + lane];  // j=256+4l..+3
        acc[0] = __fmaf_rn(qk, c0.x, acc[0]);
        acc[1] = __fmaf_rn(qk, c0.y, acc[1]);
        acc[2] = __fmaf_rn(qk, c0.z, acc[2]);
        acc[3] = __fmaf_rn(qk, c0.w, acc[3]);
        acc[4] = __fmaf_rn(qk, c1.x, acc[4]);
        acc[5] = __fmaf_rn(qk, c1.y, acc[5]);
        acc[6] = __fmaf_rn(qk, c1.z, acc[6]);
        acc[7] = __fmaf_rn(qk, c1.w, acc[7]);
    }

    unsigned long long key[8];
    {
        const float4 sq0 = *reinterpret_cast<const float4*>(sq + 4 * lane);
        const float4 sq1 = *reinterpret_cast<const float4*>(sq + 256 + 4 * lane);
        const float sqc[8] = {sq0.x, sq0.y, sq0.z, sq0.w,
                              sq1.x, sq1.y, sq1.z, sq1.w};
#pragma unroll
        for (int u = 0; u < 8; ++u) {
            const int j = (u < 4) ? (4 * lane + u) : (256 + 4 * lane + (u - 4));
            const float dd = fmaxf(
                __fsub_rn(__fadd_rn(sqr, sqc[u]), __fmul_rn(2.0f, acc[u])), 0.0f);
            key[u] = (j < P)
                ? (((unsigned long long)__float_as_uint(dd) << 32) | (unsigned)j)
                : ~0ull;
        }
    }

    unsigned long long pmin = ~0ull;
#pragma unroll
    for (int s = 0; s < 8; ++s) pmin = key[s] < pmin ? key[s] : pmin;

    unsigned long long g = ~0ull;
    for (int it = 0; it < KSEL; ++it) {
        unsigned long long v = pmin;
#pragma unroll
        for (int off = 32; off > 0; off >>= 1) {
            const unsigned long long o = __shfl_down(v, off, 64);
            v = o < v ? o : v;
        }
        g = __shfl(v, 0, 64);
        if (lane == 0) lists[(size_t)qi * CAP + it] = g;
        if (pmin == g) {            // unique winner (keys embed unique j)
#pragma unroll
            for (int s = 0; s < 8; ++s) if (key[s] == g) key[s] = ~0ull;
            pmin = ~0ull;
#pragma unroll
            for (int s = 0; s < 8; ++s) pmin = key[s] < pmin ? key[s] : pmin;
        }
    }
    if (lane == 0) { tau0[qi] = g; cnt[qi] = KSEL; }
}

// ---------------------------------------------------------------------------
// Filter (v10, unchanged from R13): bf16 MFMA screen over [512, r).
// Margin 1.5*2^-7*S is rigorous: 2*|dot err| <= 2^-6*||q||||c|| <= 2^-7*S,
// 1.5x slack for bf16-product + fp32-accum rounding.  Appends approx
// entries via one atomic per 16-lane slice (spread addresses, R9-proven).
// ---------------------------------------------------------------------------
__global__ __launch_bounds__(256)
void filter_kernel(const unsigned short* __restrict__ xb,
                   const float* __restrict__ sq,
                   const unsigned long long* __restrict__ tau0,
                   unsigned int* __restrict__ cnt,
                   unsigned long long* __restrict__ lists) {
    const int qb   = blockIdx.x;                        // 64-query tile
    const int jb   = P1LEN + blockIdx.y * FILT_CB;      // candidate tile base
    const int r_hi = min(KSEL + (qb + 1) * 64, NROWS);  // exclusive query cap
    if (jb >= r_hi) return;                             // uniform exit

    const int wave = threadIdx.x >> 6;                  // 0..3
    const int lane = threadIdx.x & 63;
    const int rb   = KSEL + qb * 64 + wave * 16;        // wave's first q row
    const int col  = lane & 15;
    const int kg   = lane >> 4;                         // k-group 0..3

    // A fragments (row rb+col, k = kg*8 + {0..7} and +32): contiguous 16B
    const int arow = min(rb + col, NROWS - 1);
    const bf16x8 a0 = *reinterpret_cast<const bf16x8*>(xb + (size_t)arow * DIM + kg * 8);
    const bf16x8 a1 = *reinterpret_cast<const bf16x8*>(xb + (size_t)arow * DIM + 32 + kg * 8);

    // Epilogue per-lane row data: D rows rb + kg*4 + i
    float sqr[4], thm[4]; int rr[4];
#pragma unroll
    for (int i = 0; i < 4; ++i) {
        const int r = rb + kg * 4 + i;
        rr[i]  = r;
        const int rc = min(r, NROWS - 1);
        sqr[i] = sq[rc];
        thm[i] = (r < NROWS) ? __uint_as_float((unsigned)(tau0[r - KSEL] >> 32))
                             : -1.0f;                   // reject all
    }

    for (int sub = 0; sub < FILT_CB / 16; ++sub) {
        const int j0 = jb + sub * 16;
        if (j0 >= r_hi) break;                          // wave-uniform
        const int j  = j0 + col;
        const int jc = min(j, NROWS - 1);
        const bf16x8 b0 = *reinterpret_cast<const bf16x8*>(xb + (size_t)jc * DIM + kg * 8);
        const bf16x8 b1 = *reinterpret_cast<const bf16x8*>(xb + (size_t)jc * DIM + 32 + kg * 8);
        f32x4 acc = {0.f, 0.f, 0.f, 0.f};
        acc = __builtin_amdgcn_mfma_f32_16x16x32_bf16(a0, b0, acc, 0, 0, 0);
        acc = __builtin_amdgcn_mfma_f32_16x16x32_bf16(a1, b1, acc, 0, 0, 0);
        const float sqc = sq[jc];
#pragma unroll
        for (int i = 0; i < 4; ++i) {
            const float s = __fadd_rn(sqr[i], sqc);
            const float d = __fmaf_rn(-2.0f, acc[i], s);
            const bool accept = (j < rr[i]) && (rr[i] < NROWS) &&
                                (d <= __fmaf_rn(0.01171875f, s, thm[i]));
            const unsigned long long mask = __ballot(accept);
            const unsigned slice = (unsigned)((mask >> (kg * 16)) & 0xFFFFull);
            if (slice) {
                const int qi = rr[i] - KSEL;            // valid: slice!=0 => accepts
                const int leader = kg * 16 + (int)__builtin_ctz(slice);
                unsigned base = 0;
                if (lane == leader)
                    base = atomicAdd(&cnt[qi], (unsigned)__popc(slice));
                base = __shfl(base, leader, 64);
                if (accept) {
                    const unsigned slot =
                        base + (unsigned)__popc(slice & ((1u << col) - 1u));
                    if (slot < CAP)
                        lists[(size_t)qi * CAP + slot] =
                            ((unsigned long long)__float_as_uint(fmaxf(d, 0.0f)) << 32)
                            | (unsigned)j;
                }
            }
        }
    }
}

// ---------------------------------------------------------------------------
// Refine (v3): FLATTENED -- one block per query, one entry per THREAD
// (s = 32 + tid, stride 256).  R13 POST-MORTEM: v2's per-lane s+=64 loop
// ran 4-15 SEQUENTIAL latency-exposed entries/lane (avg ~240 entries/query
// calibrated from WRITE_SIZE), and the allocator refused the ILP prefetch
// (VGPR 44, not ~100) -- concurrency must come from THREADS, not registers.
// v3: avg ~1 entry/thread, 4x wave count (32.6K waves), every entry in
// flight concurrently; TLP hides the 4-line row-gather latency.  Chain
// body byte-identical: exact VALIDATED fp32 k=0..63 ascending, float4
// x/y/z/w.  Entries >= 32 rewritten in place: keep iff bits <= tau_hi
// else ~0ull (inert in merge).  No atomics.
// ---------------------------------------------------------------------------
__global__ __launch_bounds__(256)
void refine_kernel(const float* __restrict__ x, const float* __restrict__ sq,
                   const unsigned long long* __restrict__ tau0,
                   const unsigned int* __restrict__ cnt,
                   unsigned long long* __restrict__ lists) {
    const int qi = blockIdx.x;                // 0..8159, one query per block
    const int r  = qi + KSEL;
    const int ne = min((int)cnt[qi], CAP);
    const unsigned th = (unsigned)(tau0[qi] >> 32);
    const float* qp = x + (size_t)r * DIM;    // block-uniform -> scalar loads
    const float  sqr = sq[r];
    unsigned long long* dst = lists + (size_t)qi * CAP;

    for (int s = KSEL + (int)threadIdx.x; s < ne; s += 256) {
        const int j = (int)(unsigned)(dst[s] & 0xFFFFFFFFu);
        const float4* cp4 = reinterpret_cast<const float4*>(x + (size_t)j * DIM);
        float4 c[16];
#pragma unroll
        for (int k = 0; k < 16; ++k) c[k] = cp4[k];
        float acc = 0.0f;
#pragma unroll
        for (int k = 0; k < 16; ++k) {
            acc = __fmaf_rn(qp[4 * k + 0], c[k].x, acc);
            acc = __fmaf_rn(qp[4 * k + 1], c[k].y, acc);
            acc = __fmaf_rn(qp[4 * k + 2], c[k].z, acc);
            acc = __fmaf_rn(qp[4 * k + 3], c[k].w, acc);
        }
        const float dd = fmaxf(
            __fsub_rn(__fadd_rn(sqr, sq[j]), __fmul_rn(2.0f, acc)), 0.0f);
        const unsigned bits = __float_as_uint(dd);
        dst[s] = (bits <= th)
                   ? (((unsigned long long)bits << 32) | (unsigned)j)
                   : ~0ull;
    }
}

// ---------------------------------------------------------------------------
// Merge: ONE WAVE per query.  16 keys/lane in registers, 32 shuffle-only
// extract-min iterations.  u64-min = ascending (dist, index), low-index
// ties (validated top_k semantics).  List is a superset of the true top-32.
// ---------------------------------------------------------------------------
__global__ __launch_bounds__(64)
void merge_kernel(const unsigned long long* __restrict__ lists,
                  const unsigned int* __restrict__ cnt,
                  float* __restrict__ out_d, float* __restrict__ out_i) {
    const int qi   = blockIdx.x;     // 0..8159
    const int lane = threadIdx.x;
    const int ne   = min((int)cnt[qi], CAP);
    const unsigned long long* src = lists + (size_t)qi * CAP;

    unsigned long long k[16];
#pragma unroll
    for (int s = 0; s < 16; ++s) {
        const int idx = lane + (s << 6);
        k[s] = (idx < ne) ? src[idx] : ~0ull;
    }
    unsigned long long pmin = ~0ull;
#pragma unroll
    for (int s = 0; s < 16; ++s) pmin = k[s] < pmin ? k[s] : pmin;

    for (int it = 0; it < KSEL; ++it) {
        unsigned long long v = pmin;
#pragma unroll
        for (int off = 32; off > 0; off >>= 1) {
            const unsigned long long o = __shfl_down(v, off, 64);
            v = o < v ? o : v;
        }
        const unsigned long long g = __shfl(v, 0, 64);
        if (lane == 0) {
            out_d[(size_t)qi * KSEL + it] = __uint_as_float((unsigned)(g >> 32));
            out_i[(size_t)qi * KSEL + it] = (float)(unsigned)(g & 0xFFFFFFFFu);
        }
        if (pmin == g) {            // unique winner rescans its registers
#pragma unroll
            for (int s = 0; s < 16; ++s) if (k[s] == g) k[s] = ~0ull;
            pmin = ~0ull;
#pragma unroll
            for (int s = 0; s < 16; ++s) pmin = k[s] < pmin ? k[s] : pmin;
        }
    }
}

extern "C" void kernel_launch(void* const* d_in, const int* in_sizes, int n_in,
                              void* d_out, int out_size, void* d_ws, size_t ws_size,
                              hipStream_t stream) {
    const float* x = (const float*)d_in[0];    // anchor_x [8192, 64] fp32
    float* sq = (float*)d_ws;                                        // 32 KB
    unsigned long long* tau0 =
        (unsigned long long*)((char*)d_ws + 32768);                  // 64 KB
    unsigned int* cnt = (unsigned int*)((char*)d_ws + 98304);        // 32 KB
    unsigned long long* lists =
        (unsigned long long*)((char*)d_ws + 131072);                 // 66.8 MB
    unsigned short* xb =
        (unsigned short*)((char*)d_ws + 66977792);                   // 1 MB bf16
    float* xT = (float*)((char*)d_ws + 68026368);                    // 2 MB fp32
    float* out_d = (float*)d_out;              // [8160, 32] distances
    float* out_i = out_d + (size_t)NQ * KSEL;  // [8160, 32] indices (as fp32)

    norms_kernel<<<NROWS / 256, 256, 0, stream>>>(x, sq);
    transpose_kernel<<<NROWS / 64, 256, 0, stream>>>(x, xT);
    convert_kernel<<<NROWS * DIM / 1024, 256, 0, stream>>>(x, xb);
    pass1_kernel<<<NQ / 4, 256, 0, stream>>>(x, xT, sq, tau0, cnt, lists);
    dim3 gf(128, (NROWS - P1LEN) / FILT_CB);   // (query tile, candidate tile)
    filter_kernel<<<gf, 256, 0, stream>>>(xb, sq, tau0, cnt, lists);
    refine_kernel<<<NQ, 256, 0, stream>>>(x, sq, tau0, cnt, lists);
    merge_kernel<<<NQ, 64, 0, stream>>>(lists, cnt, out_d, out_i);
}

// Round 15
// 335.080 us; speedup vs baseline: 2.3752x; 1.0665x over previous
//
#include <hip/hip_runtime.h>
#include <math.h>

#define NROWS 8192
#define DIM   64
#define KSEL  32
#define NQ    (NROWS - KSEL)   /* 8160 query rows */
#define P1LEN 512              /* pass-1 exact prefix */
#define CAP   1024             /* per-query candidate list capacity */
#define FILT_CB 256            /* candidates per filter block */
#define NMASK (NROWS / 16)     /* 512 bitmap words per query row */

typedef __attribute__((ext_vector_type(8))) short bf16x8;
typedef __attribute__((ext_vector_type(4))) float f32x4;

// ---------------------------------------------------------------------------
// Kernel A: row norms replicating XLA:CPU (LLVM-vectorized fused reduce):
//   VF=8 lanes, init 0, per-lane FMA chain, horizontal shuffle-tree
//   ((r0+r4)+(r2+r6)) + ((r1+r5)+(r3+r7)).   [validated bit-exact R8-R13]
// ---------------------------------------------------------------------------
__global__ void norms_kernel(const float* __restrict__ x, float* __restrict__ sq) {
    int j = blockIdx.x * blockDim.x + threadIdx.x;
    if (j >= NROWS) return;
    const float* xr = x + (size_t)j * DIM;
    float r[8];
#pragma unroll
    for (int u = 0; u < 8; ++u) r[u] = 0.0f;
#pragma unroll
    for (int i = 0; i < DIM; i += 8) {
#pragma unroll
        for (int u = 0; u < 8; ++u)
            r[u] = __fmaf_rn(xr[i + u], xr[i + u], r[u]);
    }
    const float s04 = __fadd_rn(r[0], r[4]);
    const float s26 = __fadd_rn(r[2], r[6]);
    const float s15 = __fadd_rn(r[1], r[5]);
    const float s37 = __fadd_rn(r[3], r[7]);
    sq[j] = __fadd_rn(__fadd_rn(s04, s26), __fadd_rn(s15, s37));
}

// ---------------------------------------------------------------------------
// Transpose x [8192][64] -> xT [64][8192] via LDS tile (64x64, +1 pad).
// Enables COALESCED candidate loads in pass1.
// ---------------------------------------------------------------------------
__global__ __launch_bounds__(256)
void transpose_kernel(const float* __restrict__ x, float* __restrict__ xT) {
    __shared__ float tile[64][65];
    const int jb  = blockIdx.x * 64;
    const int t   = threadIdx.x;
    const int row = t >> 2;                 // 0..63
    const int cb  = (t & 3) * 16;           // 0,16,32,48
    const float4* src = reinterpret_cast<const float4*>(
        x + (size_t)(jb + row) * DIM + cb);
#pragma unroll
    for (int i = 0; i < 4; ++i) {
        const float4 v = src[i];
        tile[row][cb + 4 * i + 0] = v.x; tile[row][cb + 4 * i + 1] = v.y;
        tile[row][cb + 4 * i + 2] = v.z; tile[row][cb + 4 * i + 3] = v.w;
    }
    __syncthreads();
    const int k = row;                      // dim index this thread writes
#pragma unroll
    for (int i = 0; i < 4; ++i) {
        float4 w;
        w.x = tile[cb + 4 * i + 0][k]; w.y = tile[cb + 4 * i + 1][k];
        w.z = tile[cb + 4 * i + 2][k]; w.w = tile[cb + 4 * i + 3][k];
        *reinterpret_cast<float4*>(xT + (size_t)k * NROWS + jb + cb + 4 * i) = w;
    }
}

// ---------------------------------------------------------------------------
// Convert x -> bf16 (RNE), 4 elems/thread.
// bf16 RNE rel-err <= 2^-8 per element -> rigorous filter margin (below).
// ---------------------------------------------------------------------------
__global__ __launch_bounds__(256)
void convert_kernel(const float* __restrict__ x, unsigned short* __restrict__ xb) {
    const int i = (blockIdx.x * blockDim.x + threadIdx.x) * 4;
    if (i >= NROWS * DIM) return;
    const float4 v = *reinterpret_cast<const float4*>(x + i);
    const float vv[4] = {v.x, v.y, v.z, v.w};
    unsigned short o[4];
#pragma unroll
    for (int u = 0; u < 4; ++u) {
        const unsigned b = __float_as_uint(vv[u]);
        o[u] = (unsigned short)((b + 0x7FFFu + ((b >> 16) & 1u)) >> 16);
    }
    *reinterpret_cast<ushort4*>(xb + i) = make_ushort4(o[0], o[1], o[2], o[3]);
}

// ---------------------------------------------------------------------------
// Pass 1 (v2, R11-validated): exact top-32 over prefix [0, min(512, r)).
// Coalesced xT candidate loads, 4 queries/block (one per wave).  Bit-exact
// chain preserved.  Selection: 8 keys/lane, 32 shuffle extract-min.
// ---------------------------------------------------------------------------
__global__ __launch_bounds__(256)
void pass1_kernel(const float* __restrict__ x, const float* __restrict__ xT,
                  const float* __restrict__ sq,
                  unsigned long long* __restrict__ tau0,
                  unsigned int* __restrict__ cnt,
                  unsigned long long* __restrict__ lists) {
    const int wave = threadIdx.x >> 6;  // 0..3: independent query per wave
    const int lane = threadIdx.x & 63;
    const int qi   = blockIdx.x * 4 + wave;   // 0..8159
    const int r    = qi + KSEL;               // query row (wave-uniform)
    const int P    = min(r, P1LEN);

    const float* qp  = x + (size_t)r * DIM;   // uniform -> scalar loads
    const float  sqr = sq[r];

    float acc[8];
#pragma unroll
    for (int u = 0; u < 8; ++u) acc[u] = 0.0f;
    const float4* xT4 = reinterpret_cast<const float4*>(xT);
#pragma unroll 4
    for (int k = 0; k < DIM; ++k) {
        const float  qk = qp[k];
        const float4 c0 = xT4[(size_t)k * (NROWS / 4) + lane];       // j=4l..+3
        const float4 c1 = xT4[(size_t)k * (NROWS / 4) + 64 + lane];  // j=256+4l..+3
        acc[0] = __fmaf_rn(qk, c0.x, acc[0]);
        acc[1] = __fmaf_rn(qk, c0.y, acc[1]);
        acc[2] = __fmaf_rn(qk, c0.z, acc[2]);
        acc[3] = __fmaf_rn(qk, c0.w, acc[3]);
        acc[4] = __fmaf_rn(qk, c1.x, acc[4]);
        acc[5] = __fmaf_rn(qk, c1.y, acc[5]);
        acc[6] = __fmaf_rn(qk, c1.z, acc[6]);
        acc[7] = __fmaf_rn(qk, c1.w, acc[7]);
    }

    unsigned long long key[8];
    {
        const float4 sq0 = *reinterpret_cast<const float4*>(sq + 4 * lane);
        const float4 sq1 = *reinterpret_cast<const float4*>(sq + 256 + 4 * lane);
        const float sqc[8] = {sq0.x, sq0.y, sq0.z, sq0.w,
                              sq1.x, sq1.y, sq1.z, sq1.w};
#pragma unroll
        for (int u = 0; u < 8; ++u) {
            const int j = (u < 4) ? (4 * lane + u) : (256 + 4 * lane + (u - 4));
            const float dd = fmaxf(
                __fsub_rn(__fadd_rn(sqr, sqc[u]), __fmul_rn(2.0f, acc[u])), 0.0f);
            key[u] = (j < P)
                ? (((unsigned long long)__float_as_uint(dd) << 32) | (unsigned)j)
                : ~0ull;
        }
    }

    unsigned long long pmin = ~0ull;
#pragma unroll
    for (int s = 0; s < 8; ++s) pmin = key[s] < pmin ? key[s] : pmin;

    unsigned long long g = ~0ull;
    for (int it = 0; it < KSEL; ++it) {
        unsigned long long v = pmin;
#pragma unroll
        for (int off = 32; off > 0; off >>= 1) {
            const unsigned long long o = __shfl_down(v, off, 64);
            v = o < v ? o : v;
        }
        g = __shfl(v, 0, 64);
        if (lane == 0) lists[(size_t)qi * CAP + it] = g;
        if (pmin == g) {            // unique winner (keys embed unique j)
#pragma unroll
            for (int s = 0; s < 8; ++s) if (key[s] == g) key[s] = ~0ull;
            pmin = ~0ull;
#pragma unroll
            for (int s = 0; s < 8; ++s) pmin = key[s] < pmin ? key[s] : pmin;
        }
    }
    if (lane == 0) { tau0[qi] = g; cnt[qi] = KSEL; }
}

// ---------------------------------------------------------------------------
// Filter (v11): bf16 MFMA screen -> BITMAP, no atomics, no list appends.
// R14 POST-MORTEM: v10's epilogue VALU issue (~18us) matched VALUBusy but
// dur was 91.6us -> ~73us idle on per-slice ballot->device-atomic(~400cy)->
// shfl->scattered-8B-store chains + 44MB write-allocate thrash.  v11: each
// (query r, 16-cand group j0) accept mask is owned by EXACTLY ONE slice of
// one wave -> store it as a 16-bit word bm[r][j0>>4].  Fire-and-forget 2-B
// store, nothing waits.  Every word refine reads is provably written (subs
// cover [512, r_hi) per block; rows with rr>=NROWS skipped).  Screen math
// and rigorous margin 1.5*2^-7*S unchanged (R9/R13-validated).
// ---------------------------------------------------------------------------
__global__ __launch_bounds__(256)
void filter_kernel(const unsigned short* __restrict__ xb,
                   const float* __restrict__ sq,
                   const unsigned long long* __restrict__ tau0,
                   unsigned short* __restrict__ bm) {
    const int qb   = blockIdx.x;                        // 64-query tile
    const int jb   = P1LEN + blockIdx.y * FILT_CB;      // candidate tile base
    const int r_hi = min(KSEL + (qb + 1) * 64, NROWS);  // exclusive query cap
    if (jb >= r_hi) return;                             // uniform exit

    const int wave = threadIdx.x >> 6;                  // 0..3
    const int lane = threadIdx.x & 63;
    const int rb   = KSEL + qb * 64 + wave * 16;        // wave's first q row
    const int col  = lane & 15;
    const int kg   = lane >> 4;                         // k-group 0..3

    // A fragments (row rb+col, k = kg*8 + {0..7} and +32): contiguous 16B
    const int arow = min(rb + col, NROWS - 1);
    const bf16x8 a0 = *reinterpret_cast<const bf16x8*>(xb + (size_t)arow * DIM + kg * 8);
    const bf16x8 a1 = *reinterpret_cast<const bf16x8*>(xb + (size_t)arow * DIM + 32 + kg * 8);

    // Epilogue per-lane row data: D rows rb + kg*4 + i
    float sqr[4], thm[4]; int rr[4];
#pragma unroll
    for (int i = 0; i < 4; ++i) {
        const int r = rb + kg * 4 + i;
        rr[i]  = r;
        const int rc = min(r, NROWS - 1);
        sqr[i] = sq[rc];
        thm[i] = (r < NROWS) ? __uint_as_float((unsigned)(tau0[r - KSEL] >> 32))
                             : -1.0f;                   // reject all
    }

    for (int sub = 0; sub < FILT_CB / 16; ++sub) {
        const int j0 = jb + sub * 16;
        if (j0 >= r_hi) break;                          // wave-uniform
        const int j  = j0 + col;
        const int jc = min(j, NROWS - 1);
        const bf16x8 b0 = *reinterpret_cast<const bf16x8*>(xb + (size_t)jc * DIM + kg * 8);
        const bf16x8 b1 = *reinterpret_cast<const bf16x8*>(xb + (size_t)jc * DIM + 32 + kg * 8);
        f32x4 acc = {0.f, 0.f, 0.f, 0.f};
        acc = __builtin_amdgcn_mfma_f32_16x16x32_bf16(a0, b0, acc, 0, 0, 0);
        acc = __builtin_amdgcn_mfma_f32_16x16x32_bf16(a1, b1, acc, 0, 0, 0);
        const float sqc = sq[jc];
#pragma unroll
        for (int i = 0; i < 4; ++i) {
            const float s = __fadd_rn(sqr[i], sqc);
            const float d = __fmaf_rn(-2.0f, acc[i], s);
            const bool accept = (j < rr[i]) &&
                                (d <= __fmaf_rn(0.01171875f, s, thm[i]));
            const unsigned long long mask = __ballot(accept);
            const unsigned slice = (unsigned)((mask >> (kg * 16)) & 0xFFFFull);
            if (col == 0 && rr[i] < NROWS)              // one writer per word
                bm[(size_t)rr[i] * NMASK + (j0 >> 4)] = (unsigned short)slice;
        }
    }
}

// ---------------------------------------------------------------------------
// Refine (v4): one block per query, bitmap-driven.  Threads read the
// query's contiguous mask row (coalesced 2B/lane), expand set bits, run
// the byte-identical exact VALIDATED fp32 chain (k=0..63 ascending, float4
// x/y/z/w), and append exact survivors (bits <= tau_hi) to lists[qi] at
// slots allocated by a block-local LDS atomic (~20cy, no device atomics).
// Thread 0 publishes cnt[qi].  Survivor set provably == v10's screen+refine.
// ---------------------------------------------------------------------------
__global__ __launch_bounds__(256)
void refine_kernel(const float* __restrict__ x, const float* __restrict__ sq,
                   const unsigned long long* __restrict__ tau0,
                   const unsigned short* __restrict__ bm,
                   unsigned int* __restrict__ cnt,
                   unsigned long long* __restrict__ lists) {
    __shared__ unsigned lcnt;
    const int qi = blockIdx.x;                // 0..8159, one query per block
    const int r  = qi + KSEL;
    if (threadIdx.x == 0) lcnt = KSEL;        // slots 0..31 are pass1's
    __syncthreads();

    const unsigned th = (unsigned)(tau0[qi] >> 32);
    const float* qp = x + (size_t)r * DIM;    // block-uniform -> scalar loads
    const float  sqr = sq[r];
    unsigned long long* dst = lists + (size_t)qi * CAP;
    const int mlast = (r - 1) >> 4;           // masks m in [32, mlast]

    for (int m = (P1LEN / 16) + (int)threadIdx.x; m <= mlast; m += 256) {
        unsigned msk = bm[(size_t)r * NMASK + m];
        while (msk) {
            const int b = __builtin_ctz(msk);
            msk &= msk - 1;
            const int j = (m << 4) + b;
            const float4* cp4 = reinterpret_cast<const float4*>(x + (size_t)j * DIM);
            float4 c[16];
#pragma unroll
            for (int k = 0; k < 16; ++k) c[k] = cp4[k];
            float acc = 0.0f;
#pragma unroll
            for (int k = 0; k < 16; ++k) {
                acc = __fmaf_rn(qp[4 * k + 0], c[k].x, acc);
                acc = __fmaf_rn(qp[4 * k + 1], c[k].y, acc);
                acc = __fmaf_rn(qp[4 * k + 2], c[k].z, acc);
                acc = __fmaf_rn(qp[4 * k + 3], c[k].w, acc);
            }
            const float dd = fmaxf(
                __fsub_rn(__fadd_rn(sqr, sq[j]), __fmul_rn(2.0f, acc)), 0.0f);
            const unsigned bits = __float_as_uint(dd);
            if (bits <= th) {
                const unsigned slot = atomicAdd(&lcnt, 1u);   // LDS atomic
                if (slot < CAP)
                    dst[slot] = ((unsigned long long)bits << 32) | (unsigned)j;
            }
        }
    }
    __syncthreads();
    if (threadIdx.x == 0) cnt[qi] = min(lcnt, (unsigned)CAP);
}

// ---------------------------------------------------------------------------
// Merge: ONE WAVE per query.  16 keys/lane in registers, 32 shuffle-only
// extract-min iterations.  u64-min = ascending (dist, index), low-index
// ties (validated top_k semantics).  List is a superset of the true top-32;
// all entries carry EXACT validated distance bits (entry order irrelevant).
// ---------------------------------------------------------------------------
__global__ __launch_bounds__(64)
void merge_kernel(const unsigned long long* __restrict__ lists,
                  const unsigned int* __restrict__ cnt,
                  float* __restrict__ out_d, float* __restrict__ out_i) {
    const int qi   = blockIdx.x;     // 0..8159
    const int lane = threadIdx.x;
    const int ne   = min((int)cnt[qi], CAP);
    const unsigned long long* src = lists + (size_t)qi * CAP;

    unsigned long long k[16];
#pragma unroll
    for (int s = 0; s < 16; ++s) {
        const int idx = lane + (s << 6);
        k[s] = (idx < ne) ? src[idx] : ~0ull;
    }
    unsigned long long pmin = ~0ull;
#pragma unroll
    for (int s = 0; s < 16; ++s) pmin = k[s] < pmin ? k[s] : pmin;

    for (int it = 0; it < KSEL; ++it) {
        unsigned long long v = pmin;
#pragma unroll
        for (int off = 32; off > 0; off >>= 1) {
            const unsigned long long o = __shfl_down(v, off, 64);
            v = o < v ? o : v;
        }
        const unsigned long long g = __shfl(v, 0, 64);
        if (lane == 0) {
            out_d[(size_t)qi * KSEL + it] = __uint_as_float((unsigned)(g >> 32));
            out_i[(size_t)qi * KSEL + it] = (float)(unsigned)(g & 0xFFFFFFFFu);
        }
        if (pmin == g) {            // unique winner rescans its registers
#pragma unroll
            for (int s = 0; s < 16; ++s) if (k[s] == g) k[s] = ~0ull;
            pmin = ~0ull;
#pragma unroll
            for (int s = 0; s < 16; ++s) pmin = k[s] < pmin ? k[s] : pmin;
        }
    }
}

extern "C" void kernel_launch(void* const* d_in, const int* in_sizes, int n_in,
                              void* d_out, int out_size, void* d_ws, size_t ws_size,
                              hipStream_t stream) {
    const float* x = (const float*)d_in[0];    // anchor_x [8192, 64] fp32
    float* sq = (float*)d_ws;                                        // 32 KB
    unsigned long long* tau0 =
        (unsigned long long*)((char*)d_ws + 32768);                  // 64 KB
    unsigned int* cnt = (unsigned int*)((char*)d_ws + 98304);        // 32 KB
    unsigned long long* lists =
        (unsigned long long*)((char*)d_ws + 131072);                 // 66.8 MB
    unsigned short* xb =
        (unsigned short*)((char*)d_ws + 66977792);                   // 1 MB bf16
    float* xT = (float*)((char*)d_ws + 68026368);                    // 2 MB fp32
    unsigned short* bm =
        (unsigned short*)((char*)d_ws + 70123520);                   // 8 MB bitmap
    float* out_d = (float*)d_out;              // [8160, 32] distances
    float* out_i = out_d + (size_t)NQ * KSEL;  // [8160, 32] indices (as fp32)

    norms_kernel<<<NROWS / 256, 256, 0, stream>>>(x, sq);
    transpose_kernel<<<NROWS / 64, 256, 0, stream>>>(x, xT);
    convert_kernel<<<NROWS * DIM / 1024, 256, 0, stream>>>(x, xb);
    pass1_kernel<<<NQ / 4, 256, 0, stream>>>(x, xT, sq, tau0, cnt, lists);
    dim3 gf(128, (NROWS - P1LEN) / FILT_CB);   // (query tile, candidate tile)
    filter_kernel<<<gf, 256, 0, stream>>>(xb, sq, tau0, bm);
    refine_kernel<<<NQ, 256, 0, stream>>>(x, sq, tau0, bm, cnt, lists);
    merge_kernel<<<NQ, 64, 0, stream>>>(lists, cnt, out_d, out_i);
}

// Round 17
// 304.839 us; speedup vs baseline: 2.6108x; 1.0992x over previous
//
#include <hip/hip_runtime.h>
#include <math.h>

#define NROWS 8192
#define DIM   64
#define KSEL  32
#define NQ    (NROWS - KSEL)   /* 8160 query rows */
#define P1LEN 512              /* pass-1 exact prefix */
#define CAP   1024             /* per-query candidate list capacity */
#define FILT_CB 256            /* candidates per filter block */
#define NMASK (NROWS / 16)     /* 512 bitmap words per query row */

typedef __attribute__((ext_vector_type(8))) short bf16x8;
typedef __attribute__((ext_vector_type(4))) float f32x4;

// ---------------------------------------------------------------------------
// Kernel A: row norms replicating XLA:CPU (LLVM-vectorized fused reduce):
//   VF=8 lanes, init 0, per-lane FMA chain, horizontal shuffle-tree
//   ((r0+r4)+(r2+r6)) + ((r1+r5)+(r3+r7)).   [validated bit-exact R8-R13]
// ---------------------------------------------------------------------------
__global__ void norms_kernel(const float* __restrict__ x, float* __restrict__ sq) {
    int j = blockIdx.x * blockDim.x + threadIdx.x;
    if (j >= NROWS) return;
    const float* xr = x + (size_t)j * DIM;
    float r[8];
#pragma unroll
    for (int u = 0; u < 8; ++u) r[u] = 0.0f;
#pragma unroll
    for (int i = 0; i < DIM; i += 8) {
#pragma unroll
        for (int u = 0; u < 8; ++u)
            r[u] = __fmaf_rn(xr[i + u], xr[i + u], r[u]);
    }
    const float s04 = __fadd_rn(r[0], r[4]);
    const float s26 = __fadd_rn(r[2], r[6]);
    const float s15 = __fadd_rn(r[1], r[5]);
    const float s37 = __fadd_rn(r[3], r[7]);
    sq[j] = __fadd_rn(__fadd_rn(s04, s26), __fadd_rn(s15, s37));
}

// ---------------------------------------------------------------------------
// Transpose x [8192][64] -> xT [64][8192] via LDS tile (64x64, +1 pad).
// Enables COALESCED candidate loads in pass1.
// ---------------------------------------------------------------------------
__global__ __launch_bounds__(256)
void transpose_kernel(const float* __restrict__ x, float* __restrict__ xT) {
    __shared__ float tile[64][65];
    const int jb  = blockIdx.x * 64;
    const int t   = threadIdx.x;
    const int row = t >> 2;                 // 0..63
    const int cb  = (t & 3) * 16;           // 0,16,32,48
    const float4* src = reinterpret_cast<const float4*>(
        x + (size_t)(jb + row) * DIM + cb);
#pragma unroll
    for (int i = 0; i < 4; ++i) {
        const float4 v = src[i];
        tile[row][cb + 4 * i + 0] = v.x; tile[row][cb + 4 * i + 1] = v.y;
        tile[row][cb + 4 * i + 2] = v.z; tile[row][cb + 4 * i + 3] = v.w;
    }
    __syncthreads();
    const int k = row;                      // dim index this thread writes
#pragma unroll
    for (int i = 0; i < 4; ++i) {
        float4 w;
        w.x = tile[cb + 4 * i + 0][k]; w.y = tile[cb + 4 * i + 1][k];
        w.z = tile[cb + 4 * i + 2][k]; w.w = tile[cb + 4 * i + 3][k];
        *reinterpret_cast<float4*>(xT + (size_t)k * NROWS + jb + cb + 4 * i) = w;
    }
}

// ---------------------------------------------------------------------------
// Convert x -> bf16 (RNE), 4 elems/thread.
// bf16 RNE rel-err <= 2^-8 per element -> rigorous filter margin (below).
// ---------------------------------------------------------------------------
__global__ __launch_bounds__(256)
void convert_kernel(const float* __restrict__ x, unsigned short* __restrict__ xb) {
    const int i = (blockIdx.x * blockDim.x + threadIdx.x) * 4;
    if (i >= NROWS * DIM) return;
    const float4 v = *reinterpret_cast<const float4*>(x + i);
    const float vv[4] = {v.x, v.y, v.z, v.w};
    unsigned short o[4];
#pragma unroll
    for (int u = 0; u < 4; ++u) {
        const unsigned b = __float_as_uint(vv[u]);
        o[u] = (unsigned short)((b + 0x7FFFu + ((b >> 16) & 1u)) >> 16);
    }
    *reinterpret_cast<ushort4*>(xb + i) = make_ushort4(o[0], o[1], o[2], o[3]);
}

// ---------------------------------------------------------------------------
// Pass 1 (v2, R11-validated): exact top-32 over prefix [0, min(512, r)).
// Coalesced xT candidate loads, 4 queries/block (one per wave).  Bit-exact
// chain preserved.  Selection: 8 keys/lane, 32 shuffle extract-min.
// ---------------------------------------------------------------------------
__global__ __launch_bounds__(256)
void pass1_kernel(const float* __restrict__ x, const float* __restrict__ xT,
                  const float* __restrict__ sq,
                  unsigned long long* __restrict__ tau0,
                  unsigned long long* __restrict__ lists) {
    const int wave = threadIdx.x >> 6;  // 0..3: independent query per wave
    const int lane = threadIdx.x & 63;
    const int qi   = blockIdx.x * 4 + wave;   // 0..8159
    const int r    = qi + KSEL;               // query row (wave-uniform)
    const int P    = min(r, P1LEN);

    const float* qp  = x + (size_t)r * DIM;   // uniform -> scalar loads
    const float  sqr = sq[r];

    float acc[8];
#pragma unroll
    for (int u = 0; u < 8; ++u) acc[u] = 0.0f;
    const float4* xT4 = reinterpret_cast<const float4*>(xT);
#pragma unroll 4
    for (int k = 0; k < DIM; ++k) {
        const float  qk = qp[k];
        const float4 c0 = xT4[(size_t)k * (NROWS / 4) + lane];       // j=4l..+3
        const float4 c1 = xT4[(size_t)k * (NROWS / 4) + 64 + lane];  // j=256+4l..+3
        acc[0] = __fmaf_rn(qk, c0.x, acc[0]);
        acc[1] = __fmaf_rn(qk, c0.y, acc[1]);
        acc[2] = __fmaf_rn(qk, c0.z, acc[2]);
        acc[3] = __fmaf_rn(qk, c0.w, acc[3]);
        acc[4] = __fmaf_rn(qk, c1.x, acc[4]);
        acc[5] = __fmaf_rn(qk, c1.y, acc[5]);
        acc[6] = __fmaf_rn(qk, c1.z, acc[6]);
        acc[7] = __fmaf_rn(qk, c1.w, acc[7]);
    }

    unsigned long long key[8];
    {
        const float4 sq0 = *reinterpret_cast<const float4*>(sq + 4 * lane);
        const float4 sq1 = *reinterpret_cast<const float4*>(sq + 256 + 4 * lane);
        const float sqc[8] = {sq0.x, sq0.y, sq0.z, sq0.w,
                              sq1.x, sq1.y, sq1.z, sq1.w};
#pragma unroll
        for (int u = 0; u < 8; ++u) {
            const int j = (u < 4) ? (4 * lane + u) : (256 + 4 * lane + (u - 4));
            const float dd = fmaxf(
                __fsub_rn(__fadd_rn(sqr, sqc[u]), __fmul_rn(2.0f, acc[u])), 0.0f);
            key[u] = (j < P)
                ? (((unsigned long long)__float_as_uint(dd) << 32) | (unsigned)j)
                : ~0ull;
        }
    }

    unsigned long long pmin = ~0ull;
#pragma unroll
    for (int s = 0; s < 8; ++s) pmin = key[s] < pmin ? key[s] : pmin;

    unsigned long long g = ~0ull;
    for (int it = 0; it < KSEL; ++it) {
        unsigned long long v = pmin;
#pragma unroll
        for (int off = 32; off > 0; off >>= 1) {
            const unsigned long long o = __shfl_down(v, off, 64);
            v = o < v ? o : v;
        }
        g = __shfl(v, 0, 64);
        if (lane == 0) lists[(size_t)qi * CAP + it] = g;
        if (pmin == g) {            // unique winner (keys embed unique j)
#pragma unroll
            for (int s = 0; s < 8; ++s) if (key[s] == g) key[s] = ~0ull;
            pmin = ~0ull;
#pragma unroll
            for (int s = 0; s < 8; ++s) pmin = key[s] < pmin ? key[s] : pmin;
        }
    }
    if (lane == 0) tau0[qi] = g;
}

// ---------------------------------------------------------------------------
// Filter (v11, R15-validated: dropped out of top-5): bf16 MFMA screen ->
// BITMAP, no atomics.  Each (query r, 16-cand group j0) accept mask is
// owned by exactly one 16-lane slice -> fire-and-forget 2-B store of
// bm[r][j0>>4].  Rigorous margin 1.5*2^-7*S (R9/R13-validated).
// ---------------------------------------------------------------------------
__global__ __launch_bounds__(256)
void filter_kernel(const unsigned short* __restrict__ xb,
                   const float* __restrict__ sq,
                   const unsigned long long* __restrict__ tau0,
                   unsigned short* __restrict__ bm) {
    const int qb   = blockIdx.x;                        // 64-query tile
    const int jb   = P1LEN + blockIdx.y * FILT_CB;      // candidate tile base
    const int r_hi = min(KSEL + (qb + 1) * 64, NROWS);  // exclusive query cap
    if (jb >= r_hi) return;                             // uniform exit

    const int wave = threadIdx.x >> 6;                  // 0..3
    const int lane = threadIdx.x & 63;
    const int rb   = KSEL + qb * 64 + wave * 16;        // wave's first q row
    const int col  = lane & 15;
    const int kg   = lane >> 4;                         // k-group 0..3

    // A fragments (row rb+col, k = kg*8 + {0..7} and +32): contiguous 16B
    const int arow = min(rb + col, NROWS - 1);
    const bf16x8 a0 = *reinterpret_cast<const bf16x8*>(xb + (size_t)arow * DIM + kg * 8);
    const bf16x8 a1 = *reinterpret_cast<const bf16x8*>(xb + (size_t)arow * DIM + 32 + kg * 8);

    // Epilogue per-lane row data: D rows rb + kg*4 + i
    float sqr[4], thm[4]; int rr[4];
#pragma unroll
    for (int i = 0; i < 4; ++i) {
        const int r = rb + kg * 4 + i;
        rr[i]  = r;
        const int rc = min(r, NROWS - 1);
        sqr[i] = sq[rc];
        thm[i] = (r < NROWS) ? __uint_as_float((unsigned)(tau0[r - KSEL] >> 32))
                             : -1.0f;                   // reject all
    }

    for (int sub = 0; sub < FILT_CB / 16; ++sub) {
        const int j0 = jb + sub * 16;
        if (j0 >= r_hi) break;                          // wave-uniform
        const int j  = j0 + col;
        const int jc = min(j, NROWS - 1);
        const bf16x8 b0 = *reinterpret_cast<const bf16x8*>(xb + (size_t)jc * DIM + kg * 8);
        const bf16x8 b1 = *reinterpret_cast<const bf16x8*>(xb + (size_t)jc * DIM + 32 + kg * 8);
        f32x4 acc = {0.f, 0.f, 0.f, 0.f};
        acc = __builtin_amdgcn_mfma_f32_16x16x32_bf16(a0, b0, acc, 0, 0, 0);
        acc = __builtin_amdgcn_mfma_f32_16x16x32_bf16(a1, b1, acc, 0, 0, 0);
        const float sqc = sq[jc];
#pragma unroll
        for (int i = 0; i < 4; ++i) {
            const float s = __fadd_rn(sqr[i], sqc);
            const float d = __fmaf_rn(-2.0f, acc[i], s);
            const bool accept = (j < rr[i]) &&
                                (d <= __fmaf_rn(0.01171875f, s, thm[i]));
            const unsigned long long mask = __ballot(accept);
            const unsigned slice = (unsigned)((mask >> (kg * 16)) & 0xFFFFull);
            if (col == 0 && rr[i] < NROWS)              // one writer per word
                bm[(size_t)rr[i] * NMASK + (j0 >> 4)] = (unsigned short)slice;
        }
    }
}

// ---------------------------------------------------------------------------
// Refine+Merge (v5, FUSED): one block per query.  R15 POST-MORTEM: refine
// wrote ~15MB of survivor keys to lists (L2) only for merge to re-read
// them in a separate 8160-block dispatch -- a pure structural round-trip,
// since query qi's survivors are produced AND consumed by one block.  v5:
//   * stage pass1's 32 exact keys from lists into LDS keys[0..31];
//   * bitmap-scan + byte-identical exact fp32 chain (k=0..63 ascending,
//     float4 x/y/z/w); exact survivors (bits <= tau_hi) appended to the
//     LDS key array via LDS atomic (~500 max << 1024 cap);
//   * __syncthreads; wave 0 runs the validated 16-keys/lane shuffle
//     extract-min (u64 min = ascending (dist, idx), low-index ties)
//     straight from LDS and writes out_d / out_i.
// Key set and tie semantics provably identical to split refine+merge.
// LDS 8.2KB -> no occupancy impact.  merge_kernel deleted.
// ---------------------------------------------------------------------------
__global__ __launch_bounds__(256)
void refine_merge_kernel(const float* __restrict__ x, const float* __restrict__ sq,
                         const unsigned long long* __restrict__ tau0,
                         const unsigned short* __restrict__ bm,
                         const unsigned long long* __restrict__ lists,
                         float* __restrict__ out_d, float* __restrict__ out_i) {
    __shared__ unsigned long long keys[CAP];
    __shared__ unsigned lcnt;
    const int qi  = blockIdx.x;               // 0..8159, one query per block
    const int r   = qi + KSEL;
    const int tid = threadIdx.x;
    if (tid == 0) lcnt = KSEL;
    if (tid < KSEL) keys[tid] = lists[(size_t)qi * CAP + tid];  // pass1 keys
    __syncthreads();

    const unsigned th = (unsigned)(tau0[qi] >> 32);
    const float* qp = x + (size_t)r * DIM;    // block-uniform -> scalar loads
    const float  sqr = sq[r];
    const int mlast = (r - 1) >> 4;           // masks m in [32, mlast]

    for (int m = (P1LEN / 16) + tid; m <= mlast; m += 256) {
        unsigned msk = bm[(size_t)r * NMASK + m];
        while (msk) {
            const int b = __builtin_ctz(msk);
            msk &= msk - 1;
            const int j = (m << 4) + b;
            const float4* cp4 = reinterpret_cast<const float4*>(x + (size_t)j * DIM);
            float4 c[16];
#pragma unroll
            for (int k = 0; k < 16; ++k) c[k] = cp4[k];
            float acc = 0.0f;
#pragma unroll
            for (int k = 0; k < 16; ++k) {
                acc = __fmaf_rn(qp[4 * k + 0], c[k].x, acc);
                acc = __fmaf_rn(qp[4 * k + 1], c[k].y, acc);
                acc = __fmaf_rn(qp[4 * k + 2], c[k].z, acc);
                acc = __fmaf_rn(qp[4 * k + 3], c[k].w, acc);
            }
            const float dd = fmaxf(
                __fsub_rn(__fadd_rn(sqr, sq[j]), __fmul_rn(2.0f, acc)), 0.0f);
            const unsigned bits = __float_as_uint(dd);
            if (bits <= th) {
                const unsigned slot = atomicAdd(&lcnt, 1u);   // LDS atomic
                if (slot < CAP)
                    keys[slot] = ((unsigned long long)bits << 32) | (unsigned)j;
            }
        }
    }
    __syncthreads();

    if (tid >= 64) return;                    // wave 0 does the selection
    const int lane = tid;
    const int ne   = min((int)lcnt, CAP);

    unsigned long long k[16];
#pragma unroll
    for (int s = 0; s < 16; ++s) {
        const int idx = lane + (s << 6);
        k[s] = (idx < ne) ? keys[idx] : ~0ull;
    }
    unsigned long long pmin = ~0ull;
#pragma unroll
    for (int s = 0; s < 16; ++s) pmin = k[s] < pmin ? k[s] : pmin;

    for (int it = 0; it < KSEL; ++it) {
        unsigned long long v = pmin;
#pragma unroll
        for (int off = 32; off > 0; off >>= 1) {
            const unsigned long long o = __shfl_down(v, off, 64);
            v = o < v ? o : v;
        }
        const unsigned long long g = __shfl(v, 0, 64);
        if (lane == 0) {
            out_d[(size_t)qi * KSEL + it] = __uint_as_float((unsigned)(g >> 32));
            out_i[(size_t)qi * KSEL + it] = (float)(unsigned)(g & 0xFFFFFFFFu);
        }
        if (pmin == g) {            // unique winner rescans its registers
#pragma unroll
            for (int s = 0; s < 16; ++s) if (k[s] == g) k[s] = ~0ull;
            pmin = ~0ull;
#pragma unroll
            for (int s = 0; s < 16; ++s) pmin = k[s] < pmin ? k[s] : pmin;
        }
    }
}

extern "C" void kernel_launch(void* const* d_in, const int* in_sizes, int n_in,
                              void* d_out, int out_size, void* d_ws, size_t ws_size,
                              hipStream_t stream) {
    const float* x = (const float*)d_in[0];    // anchor_x [8192, 64] fp32
    float* sq = (float*)d_ws;                                        // 32 KB
    unsigned long long* tau0 =
        (unsigned long long*)((char*)d_ws + 32768);                  // 64 KB
    unsigned long long* lists =
        (unsigned long long*)((char*)d_ws + 131072);                 // 66.8 MB
    unsigned short* xb =
        (unsigned short*)((char*)d_ws + 66977792);                   // 1 MB bf16
    float* xT = (float*)((char*)d_ws + 68026368);                    // 2 MB fp32
    unsigned short* bm =
        (unsigned short*)((char*)d_ws + 70123520);                   // 8 MB bitmap
    float* out_d = (float*)d_out;              // [8160, 32] distances
    float* out_i = out_d + (size_t)NQ * KSEL;  // [8160, 32] indices (as fp32)

    norms_kernel<<<NROWS / 256, 256, 0, stream>>>(x, sq);
    transpose_kernel<<<NROWS / 64, 256, 0, stream>>>(x, xT);
    convert_kernel<<<NROWS * DIM / 1024, 256, 0, stream>>>(x, xb);
    pass1_kernel<<<NQ / 4, 256, 0, stream>>>(x, xT, sq, tau0, lists);
    dim3 gf(128, (NROWS - P1LEN) / FILT_CB);   // (query tile, candidate tile)
    filter_kernel<<<gf, 256, 0, stream>>>(xb, sq, tau0, bm);
    refine_merge_kernel<<<NQ, 256, 0, stream>>>(x, sq, tau0, bm, lists,
                                                out_d, out_i);
}

// Round 19
// 284.085 us; speedup vs baseline: 2.8016x; 1.0731x over previous
//
#include <hip/hip_runtime.h>
#include <math.h>

#define NROWS 8192
#define DIM   64
#define KSEL  32
#define NQ    (NROWS - KSEL)   /* 8160 query rows */
#define P1LEN 512              /* pass-1 exact prefix */
#define CAP   1024             /* per-query candidate list capacity */
#define FILT_CB 256            /* candidates per filter block */
#define NMASK (NROWS / 16)     /* 512 bitmap words per query row */

typedef __attribute__((ext_vector_type(8))) short bf16x8;
typedef __attribute__((ext_vector_type(4))) float f32x4;

// ---------------------------------------------------------------------------
// Kernel A: row norms replicating XLA:CPU (LLVM-vectorized fused reduce):
//   VF=8 lanes, init 0, per-lane FMA chain, horizontal shuffle-tree
//   ((r0+r4)+(r2+r6)) + ((r1+r5)+(r3+r7)).   [validated bit-exact R8-R13]
// ---------------------------------------------------------------------------
__global__ void norms_kernel(const float* __restrict__ x, float* __restrict__ sq) {
    int j = blockIdx.x * blockDim.x + threadIdx.x;
    if (j >= NROWS) return;
    const float* xr = x + (size_t)j * DIM;
    float r[8];
#pragma unroll
    for (int u = 0; u < 8; ++u) r[u] = 0.0f;
#pragma unroll
    for (int i = 0; i < DIM; i += 8) {
#pragma unroll
        for (int u = 0; u < 8; ++u)
            r[u] = __fmaf_rn(xr[i + u], xr[i + u], r[u]);
    }
    const float s04 = __fadd_rn(r[0], r[4]);
    const float s26 = __fadd_rn(r[2], r[6]);
    const float s15 = __fadd_rn(r[1], r[5]);
    const float s37 = __fadd_rn(r[3], r[7]);
    sq[j] = __fadd_rn(__fadd_rn(s04, s26), __fadd_rn(s15, s37));
}

// ---------------------------------------------------------------------------
// Transpose x [8192][64] -> xT [64][8192] via LDS tile (64x64, +1 pad).
// Enables COALESCED candidate loads in pass1.
// ---------------------------------------------------------------------------
__global__ __launch_bounds__(256)
void transpose_kernel(const float* __restrict__ x, float* __restrict__ xT) {
    __shared__ float tile[64][65];
    const int jb  = blockIdx.x * 64;
    const int t   = threadIdx.x;
    const int row = t >> 2;                 // 0..63
    const int cb  = (t & 3) * 16;           // 0,16,32,48
    const float4* src = reinterpret_cast<const float4*>(
        x + (size_t)(jb + row) * DIM + cb);
#pragma unroll
    for (int i = 0; i < 4; ++i) {
        const float4 v = src[i];
        tile[row][cb + 4 * i + 0] = v.x; tile[row][cb + 4 * i + 1] = v.y;
        tile[row][cb + 4 * i + 2] = v.z; tile[row][cb + 4 * i + 3] = v.w;
    }
    __syncthreads();
    const int k = row;                      // dim index this thread writes
#pragma unroll
    for (int i = 0; i < 4; ++i) {
        float4 w;
        w.x = tile[cb + 4 * i + 0][k]; w.y = tile[cb + 4 * i + 1][k];
        w.z = tile[cb + 4 * i + 2][k]; w.w = tile[cb + 4 * i + 3][k];
        *reinterpret_cast<float4*>(xT + (size_t)k * NROWS + jb + cb + 4 * i) = w;
    }
}

// ---------------------------------------------------------------------------
// Convert x -> bf16 (RNE), 4 elems/thread.
// bf16 RNE rel-err <= 2^-8 per element -> rigorous filter margin (below).
// ---------------------------------------------------------------------------
__global__ __launch_bounds__(256)
void convert_kernel(const float* __restrict__ x, unsigned short* __restrict__ xb) {
    const int i = (blockIdx.x * blockDim.x + threadIdx.x) * 4;
    if (i >= NROWS * DIM) return;
    const float4 v = *reinterpret_cast<const float4*>(x + i);
    const float vv[4] = {v.x, v.y, v.z, v.w};
    unsigned short o[4];
#pragma unroll
    for (int u = 0; u < 4; ++u) {
        const unsigned b = __float_as_uint(vv[u]);
        o[u] = (unsigned short)((b + 0x7FFFu + ((b >> 16) & 1u)) >> 16);
    }
    *reinterpret_cast<ushort4*>(xb + i) = make_ushort4(o[0], o[1], o[2], o[3]);
}

// ---------------------------------------------------------------------------
// Pass 1 (v2, R11-validated): exact top-32 over prefix [0, min(512, r)).
// Coalesced xT candidate loads, 4 queries/block (one per wave).  Bit-exact
// chain preserved.  Selection: 8 keys/lane, 32 shuffle extract-min.
// ---------------------------------------------------------------------------
__global__ __launch_bounds__(256)
void pass1_kernel(const float* __restrict__ x, const float* __restrict__ xT,
                  const float* __restrict__ sq,
                  unsigned long long* __restrict__ tau0,
                  unsigned long long* __restrict__ lists) {
    const int wave = threadIdx.x >> 6;  // 0..3: independent query per wave
    const int lane = threadIdx.x & 63;
    const int qi   = blockIdx.x * 4 + wave;   // 0..8159
    const int r    = qi + KSEL;               // query row (wave-uniform)
    const int P    = min(r, P1LEN);

    const float* qp  = x + (size_t)r * DIM;   // uniform -> scalar loads
    const float  sqr = sq[r];

    float acc[8];
#pragma unroll
    for (int u = 0; u < 8; ++u) acc[u] = 0.0f;
    const float4* xT4 = reinterpret_cast<const float4*>(xT);
#pragma unroll 4
    for (int k = 0; k < DIM; ++k) {
        const float  qk = qp[k];
        const float4 c0 = xT4[(size_t)k * (NROWS / 4) + lane];       // j=4l..+3
        const float4 c1 = xT4[(size_t)k * (NROWS / 4) + 64 + lane];  // j=256+4l..+3
        acc[0] = __fmaf_rn(qk, c0.x, acc[0]);
        acc[1] = __fmaf_rn(qk, c0.y, acc[1]);
        acc[2] = __fmaf_rn(qk, c0.z, acc[2]);
        acc[3] = __fmaf_rn(qk, c0.w, acc[3]);
        acc[4] = __fmaf_rn(qk, c1.x, acc[4]);
        acc[5] = __fmaf_rn(qk, c1.y, acc[5]);
        acc[6] = __fmaf_rn(qk, c1.z, acc[6]);
        acc[7] = __fmaf_rn(qk, c1.w, acc[7]);
    }

    unsigned long long key[8];
    {
        const float4 sq0 = *reinterpret_cast<const float4*>(sq + 4 * lane);
        const float4 sq1 = *reinterpret_cast<const float4*>(sq + 256 + 4 * lane);
        const float sqc[8] = {sq0.x, sq0.y, sq0.z, sq0.w,
                              sq1.x, sq1.y, sq1.z, sq1.w};
#pragma unroll
        for (int u = 0; u < 8; ++u) {
            const int j = (u < 4) ? (4 * lane + u) : (256 + 4 * lane + (u - 4));
            const float dd = fmaxf(
                __fsub_rn(__fadd_rn(sqr, sqc[u]), __fmul_rn(2.0f, acc[u])), 0.0f);
            key[u] = (j < P)
                ? (((unsigned long long)__float_as_uint(dd) << 32) | (unsigned)j)
                : ~0ull;
        }
    }

    unsigned long long pmin = ~0ull;
#pragma unroll
    for (int s = 0; s < 8; ++s) pmin = key[s] < pmin ? key[s] : pmin;

    unsigned long long g = ~0ull;
    for (int it = 0; it < KSEL; ++it) {
        unsigned long long v = pmin;
#pragma unroll
        for (int off = 32; off > 0; off >>= 1) {
            const unsigned long long o = __shfl_down(v, off, 64);
            v = o < v ? o : v;
        }
        g = __shfl(v, 0, 64);
        if (lane == 0) lists[(size_t)qi * CAP + it] = g;
        if (pmin == g) {            // unique winner (keys embed unique j)
#pragma unroll
            for (int s = 0; s < 8; ++s) if (key[s] == g) key[s] = ~0ull;
            pmin = ~0ull;
#pragma unroll
            for (int s = 0; s < 8; ++s) pmin = key[s] < pmin ? key[s] : pmin;
        }
    }
    if (lane == 0) tau0[qi] = g;
}

// ---------------------------------------------------------------------------
// Filter (v11, R15-validated): bf16 MFMA screen -> BITMAP, no atomics.
// Each (query r, 16-cand group j0) accept mask is owned by exactly one
// 16-lane slice -> fire-and-forget 2-B store of bm[r][j0>>4].  Rigorous
// margin 1.5*2^-7*S (R9/R13-validated).
// ---------------------------------------------------------------------------
__global__ __launch_bounds__(256)
void filter_kernel(const unsigned short* __restrict__ xb,
                   const float* __restrict__ sq,
                   const unsigned long long* __restrict__ tau0,
                   unsigned short* __restrict__ bm) {
    const int qb   = blockIdx.x;                        // 64-query tile
    const int jb   = P1LEN + blockIdx.y * FILT_CB;      // candidate tile base
    const int r_hi = min(KSEL + (qb + 1) * 64, NROWS);  // exclusive query cap
    if (jb >= r_hi) return;                             // uniform exit

    const int wave = threadIdx.x >> 6;                  // 0..3
    const int lane = threadIdx.x & 63;
    const int rb   = KSEL + qb * 64 + wave * 16;        // wave's first q row
    const int col  = lane & 15;
    const int kg   = lane >> 4;                         // k-group 0..3

    // A fragments (row rb+col, k = kg*8 + {0..7} and +32): contiguous 16B
    const int arow = min(rb + col, NROWS - 1);
    const bf16x8 a0 = *reinterpret_cast<const bf16x8*>(xb + (size_t)arow * DIM + kg * 8);
    const bf16x8 a1 = *reinterpret_cast<const bf16x8*>(xb + (size_t)arow * DIM + 32 + kg * 8);

    // Epilogue per-lane row data: D rows rb + kg*4 + i
    float sqr[4], thm[4]; int rr[4];
#pragma unroll
    for (int i = 0; i < 4; ++i) {
        const int r = rb + kg * 4 + i;
        rr[i]  = r;
        const int rc = min(r, NROWS - 1);
        sqr[i] = sq[rc];
        thm[i] = (r < NROWS) ? __uint_as_float((unsigned)(tau0[r - KSEL] >> 32))
                             : -1.0f;                   // reject all
    }

    for (int sub = 0; sub < FILT_CB / 16; ++sub) {
        const int j0 = jb + sub * 16;
        if (j0 >= r_hi) break;                          // wave-uniform
        const int j  = j0 + col;
        const int jc = min(j, NROWS - 1);
        const bf16x8 b0 = *reinterpret_cast<const bf16x8*>(xb + (size_t)jc * DIM + kg * 8);
        const bf16x8 b1 = *reinterpret_cast<const bf16x8*>(xb + (size_t)jc * DIM + 32 + kg * 8);
        f32x4 acc = {0.f, 0.f, 0.f, 0.f};
        acc = __builtin_amdgcn_mfma_f32_16x16x32_bf16(a0, b0, acc, 0, 0, 0);
        acc = __builtin_amdgcn_mfma_f32_16x16x32_bf16(a1, b1, acc, 0, 0, 0);
        const float sqc = sq[jc];
#pragma unroll
        for (int i = 0; i < 4; ++i) {
            const float s = __fadd_rn(sqr[i], sqc);
            const float d = __fmaf_rn(-2.0f, acc[i], s);
            const bool accept = (j < rr[i]) &&
                                (d <= __fmaf_rn(0.01171875f, s, thm[i]));
            const unsigned long long mask = __ballot(accept);
            const unsigned slice = (unsigned)((mask >> (kg * 16)) & 0xFFFFull);
            if (col == 0 && rr[i] < NROWS)              // one writer per word
                bm[(size_t)rr[i] * NMASK + (j0 >> 4)] = (unsigned short)slice;
        }
    }
}

// ---------------------------------------------------------------------------
// Refine+Merge (v6): 128-thread blocks, load-balanced 3-phase.
// R17 POST-MORTEM: v5 at 146us, VALU 47%, Occ 45% -- two wastes: (a) chain
// phase ran under while(msk) divergence (~20% lane utilization: wave pays
// max-over-lanes chain rounds); (b) 3 of 4 waves exited before selection,
// idling 75% of wave slots for the ~13Kcy serialized-bpermute extract-min.
// v6:  Phase A: compact accepted j's into LDS jlist (ctz + LDS atomic --
//      cheap, no chains under divergence).
//      Phase B: process jlist ROUND-ROBIN (idx = tid; idx += 128): jcnt is
//      block-uniform, so every round runs 128 concurrent perfectly-balanced
//      chains (byte-identical exact fp32 k=0..63 ascending, float4
//      x/y/z/w); exact survivors appended to LDS keys via LDS atomic.
//      Phase C: wave 0 runs the unchanged 16-keys/lane extract-min.
// 128 thr + 10.3KB LDS -> 15 blocks x 2 waves = ~30 waves/CU; only 1 wave
// idles during selection.  Key set / drop semantics / tie order unchanged.
// ---------------------------------------------------------------------------
__global__ __launch_bounds__(128)
void refine_merge_kernel(const float* __restrict__ x, const float* __restrict__ sq,
                         const unsigned long long* __restrict__ tau0,
                         const unsigned short* __restrict__ bm,
                         const unsigned long long* __restrict__ lists,
                         float* __restrict__ out_d, float* __restrict__ out_i) {
    __shared__ unsigned long long keys[CAP];
    __shared__ unsigned short jlist[CAP];
    __shared__ unsigned jcnt_s, lcnt;
    const int qi  = blockIdx.x;               // 0..8159, one query per block
    const int r   = qi + KSEL;
    const int tid = threadIdx.x;
    if (tid == 0) { jcnt_s = 0; lcnt = KSEL; }
    if (tid < KSEL) keys[tid] = lists[(size_t)qi * CAP + tid];  // pass1 keys
    __syncthreads();

    // ---- Phase A: compact accepted candidate indices into jlist
    const int mlast = (r - 1) >> 4;           // masks m in [32, mlast]
    for (int m = (P1LEN / 16) + tid; m <= mlast; m += 128) {
        unsigned msk = bm[(size_t)r * NMASK + m];
        while (msk) {
            const int b = __builtin_ctz(msk);
            msk &= msk - 1;
            const unsigned slot = atomicAdd(&jcnt_s, 1u);     // LDS atomic
            if (slot < CAP) jlist[slot] = (unsigned short)((m << 4) + b);
        }
    }
    __syncthreads();

    // ---- Phase B: balanced exact chains over the compacted list
    const unsigned jcnt = min(jcnt_s, (unsigned)CAP);
    const unsigned th = (unsigned)(tau0[qi] >> 32);
    const float* qp = x + (size_t)r * DIM;    // block-uniform -> scalar loads
    const float  sqr = sq[r];
    for (unsigned idx = tid; idx < jcnt; idx += 128) {
        const int j = (int)jlist[idx];
        const float4* cp4 = reinterpret_cast<const float4*>(x + (size_t)j * DIM);
        float4 c[16];
#pragma unroll
        for (int k = 0; k < 16; ++k) c[k] = cp4[k];
        float acc = 0.0f;
#pragma unroll
        for (int k = 0; k < 16; ++k) {
            acc = __fmaf_rn(qp[4 * k + 0], c[k].x, acc);
            acc = __fmaf_rn(qp[4 * k + 1], c[k].y, acc);
            acc = __fmaf_rn(qp[4 * k + 2], c[k].z, acc);
            acc = __fmaf_rn(qp[4 * k + 3], c[k].w, acc);
        }
        const float dd = fmaxf(
            __fsub_rn(__fadd_rn(sqr, sq[j]), __fmul_rn(2.0f, acc)), 0.0f);
        const unsigned bits = __float_as_uint(dd);
        if (bits <= th) {
            const unsigned slot = atomicAdd(&lcnt, 1u);       // LDS atomic
            if (slot < CAP)
                keys[slot] = ((unsigned long long)bits << 32) | (unsigned)j;
        }
    }
    __syncthreads();

    // ---- Phase C: wave 0 extract-min (validated 16-keys/lane structure)
    if (tid >= 64) return;
    const int lane = tid;
    const int ne   = min((int)lcnt, CAP);

    unsigned long long k[16];
#pragma unroll
    for (int s = 0; s < 16; ++s) {
        const int idx = lane + (s << 6);
        k[s] = (idx < ne) ? keys[idx] : ~0ull;
    }
    unsigned long long pmin = ~0ull;
#pragma unroll
    for (int s = 0; s < 16; ++s) pmin = k[s] < pmin ? k[s] : pmin;

    for (int it = 0; it < KSEL; ++it) {
        unsigned long long v = pmin;
#pragma unroll
        for (int off = 32; off > 0; off >>= 1) {
            const unsigned long long o = __shfl_down(v, off, 64);
            v = o < v ? o : v;
        }
        const unsigned long long g = __shfl(v, 0, 64);
        if (lane == 0) {
            out_d[(size_t)qi * KSEL + it] = __uint_as_float((unsigned)(g >> 32));
            out_i[(size_t)qi * KSEL + it] = (float)(unsigned)(g & 0xFFFFFFFFu);
        }
        if (pmin == g) {            // unique winner rescans its registers
#pragma unroll
            for (int s = 0; s < 16; ++s) if (k[s] == g) k[s] = ~0ull;
            pmin = ~0ull;
#pragma unroll
            for (int s = 0; s < 16; ++s) pmin = k[s] < pmin ? k[s] : pmin;
        }
    }
}

extern "C" void kernel_launch(void* const* d_in, const int* in_sizes, int n_in,
                              void* d_out, int out_size, void* d_ws, size_t ws_size,
                              hipStream_t stream) {
    const float* x = (const float*)d_in[0];    // anchor_x [8192, 64] fp32
    float* sq = (float*)d_ws;                                        // 32 KB
    unsigned long long* tau0 =
        (unsigned long long*)((char*)d_ws + 32768);                  // 64 KB
    unsigned long long* lists =
        (unsigned long long*)((char*)d_ws + 131072);                 // 66.8 MB
    unsigned short* xb =
        (unsigned short*)((char*)d_ws + 66977792);                   // 1 MB bf16
    float* xT = (float*)((char*)d_ws + 68026368);                    // 2 MB fp32
    unsigned short* bm =
        (unsigned short*)((char*)d_ws + 70123520);                   // 8 MB bitmap
    float* out_d = (float*)d_out;              // [8160, 32] distances
    float* out_i = out_d + (size_t)NQ * KSEL;  // [8160, 32] indices (as fp32)

    norms_kernel<<<NROWS / 256, 256, 0, stream>>>(x, sq);
    transpose_kernel<<<NROWS / 64, 256, 0, stream>>>(x, xT);
    convert_kernel<<<NROWS * DIM / 1024, 256, 0, stream>>>(x, xb);
    pass1_kernel<<<NQ / 4, 256, 0, stream>>>(x, xT, sq, tau0, lists);
    dim3 gf(128, (NROWS - P1LEN) / FILT_CB);   // (query tile, candidate tile)
    filter_kernel<<<gf, 256, 0, stream>>>(xb, sq, tau0, bm);
    refine_merge_kernel<<<NQ, 128, 0, stream>>>(x, sq, tau0, bm, lists,
                                                out_d, out_i);
}